// Round 2
// baseline (1611.908 us; speedup 1.0000x reference)
//
#include <hip/hip_runtime.h>
#include <hip/hip_bf16.h>

#define D_MODEL 1024
#define D_INNER 2048
#define NPROJ   4096   /* 2*D_INNER */
#define D_STATE 16
#define DT_RANK 128
#define XPJ_N   160    /* DT_RANK + 2*D_STATE */
#define SEQLEN  1024
#define BATCH   2
#define NTOK    2048   /* BATCH*SEQLEN */

__device__ __forceinline__ float sigmoidf_(float x) { return 1.f / (1.f + __expf(-x)); }

// ---------------- LayerNorm: one block per row (NTOK rows of D_MODEL) ----------------
__global__ __launch_bounds__(256) void ln_kernel(const float* __restrict__ x,
                                                 const float* __restrict__ g,
                                                 const float* __restrict__ be,
                                                 float* __restrict__ h)
{
    int row = blockIdx.x;
    const float4* xr = (const float4*)(x + (long)row * D_MODEL);
    float4 v = xr[threadIdx.x];
    float s1 = v.x + v.y + v.z + v.w;
    float s2 = v.x*v.x + v.y*v.y + v.z*v.z + v.w*v.w;
    for (int off = 32; off >= 1; off >>= 1) {
        s1 += __shfl_down(s1, off);
        s2 += __shfl_down(s2, off);
    }
    __shared__ float red[8];
    int wid = threadIdx.x >> 6;
    if ((threadIdx.x & 63) == 0) { red[wid] = s1; red[4 + wid] = s2; }
    __syncthreads();
    float mu  = (red[0] + red[1] + red[2] + red[3]) * (1.f / D_MODEL);
    float ex2 = (red[4] + red[5] + red[6] + red[7]) * (1.f / D_MODEL);
    float inv = rsqrtf(ex2 - mu * mu + 1e-5f);
    float4 g4 = ((const float4*)g)[threadIdx.x];
    float4 b4 = ((const float4*)be)[threadIdx.x];
    float4 o;
    o.x = (v.x - mu) * inv * g4.x + b4.x;
    o.y = (v.y - mu) * inv * g4.y + b4.y;
    o.z = (v.z - mu) * inv * g4.z + b4.z;
    o.w = (v.w - mu) * inv * g4.w + b4.w;
    ((float4*)(h + (long)row * D_MODEL))[threadIdx.x] = o;
}

// ---------------- Generic f32 tiled GEMM, C[M,N] = A[M,K(lda)] * B[K,N(ldb)] ----------
// EPI 0: Cf = acc
// EPI 1: Cf = softplus(acc + bias[n])
// EPI 2: Cf = acc + resid[m*N+n]
template <int EPI>
__global__ __launch_bounds__(256) void gemm_kernel(const float* __restrict__ A, int lda,
                                                   const float* __restrict__ B, int ldb,
                                                   const float* __restrict__ bias,
                                                   const float* __restrict__ resid,
                                                   float* __restrict__ Cf,
                                                   int M, int N, int K, int ldc)
{
    __shared__ float As[64][17];
    __shared__ float Bs[16][65];
    int tid = threadIdx.x;
    int tx = tid & 15, ty = tid >> 4;
    int m0 = blockIdx.y * 64, n0 = blockIdx.x * 64;
    float acc[4][4] = {};
    for (int k0 = 0; k0 < K; k0 += 16) {
        #pragma unroll
        for (int i = 0; i < 4; ++i) {
            int idx = tid + i * 256;
            int r = idx >> 4, c = idx & 15;
            As[r][c] = A[(long)(m0 + r) * lda + (k0 + c)];  // M,K always tile-divisible
        }
        #pragma unroll
        for (int i = 0; i < 4; ++i) {
            int idx = tid + i * 256;
            int r = idx >> 6, c = idx & 63;
            int gn = n0 + c;
            Bs[r][c] = (gn < N) ? B[(long)(k0 + r) * ldb + gn] : 0.f;
        }
        __syncthreads();
        #pragma unroll
        for (int kk = 0; kk < 16; ++kk) {
            float a[4], b[4];
            #pragma unroll
            for (int i = 0; i < 4; ++i) a[i] = As[ty * 4 + i][kk];
            #pragma unroll
            for (int j = 0; j < 4; ++j) b[j] = Bs[kk][tx * 4 + j];
            #pragma unroll
            for (int i = 0; i < 4; ++i)
                #pragma unroll
                for (int j = 0; j < 4; ++j) acc[i][j] += a[i] * b[j];
        }
        __syncthreads();
    }
    #pragma unroll
    for (int i = 0; i < 4; ++i) {
        int gm = m0 + ty * 4 + i;
        #pragma unroll
        for (int j = 0; j < 4; ++j) {
            int gn = n0 + tx * 4 + j;
            if (gn >= N) continue;
            float v = acc[i][j];
            if (EPI == 1) {
                v += bias[gn];
                v = (v > 20.f) ? v : log1pf(__expf(v));
                Cf[(long)gm * ldc + gn] = v;
            } else if (EPI == 2) {
                v += resid[(long)gm * N + gn];
                Cf[(long)gm * ldc + gn] = v;
            } else {
                Cf[(long)gm * ldc + gn] = v;
            }
        }
    }
}

// ---------------- depthwise causal conv (width 4) + bias + SiLU ----------------
// xz layout: [NTOK, 4096]; xb_raw = cols [0,2048). Output xb [NTOK, 2048].
__global__ __launch_bounds__(256) void conv_silu_kernel(const float* __restrict__ xz,
                                                        const float* __restrict__ cw,
                                                        const float* __restrict__ cb,
                                                        float* __restrict__ xb)
{
    long i = (long)blockIdx.x * 256 + threadIdx.x;  // over NTOK*D_INNER
    int d = (int)(i & (D_INNER - 1));
    long tok = i >> 11;
    int l = (int)(tok & (SEQLEN - 1));
    float w0 = cw[d * 4 + 0], w1 = cw[d * 4 + 1], w2 = cw[d * 4 + 2], w3 = cw[d * 4 + 3];
    float acc = cb[d];
    acc += xz[tok * NPROJ + d] * w3;
    if (l >= 1) acc += xz[(tok - 1) * NPROJ + d] * w2;
    if (l >= 2) acc += xz[(tok - 2) * NPROJ + d] * w1;
    if (l >= 3) acc += xz[(tok - 3) * NPROJ + d] * w0;
    xb[i] = acc * sigmoidf_(acc);
}

// ---------------- selective scan: 16 lanes (one per state) per (b,d) channel ---------
// Fused epilogue: yfin = (scan_y + xb*D) * silu(z)
__global__ __launch_bounds__(256) void scan_kernel(const float* __restrict__ delta,
                                                   const float* __restrict__ xb,
                                                   const float* __restrict__ xpj,
                                                   const float* __restrict__ xz,
                                                   const float* __restrict__ A_log,
                                                   const float* __restrict__ Dp,
                                                   float* __restrict__ yfin)
{
    int tid = threadIdx.x;
    int lane = tid & 15, grp = tid >> 4;
    int gidx = blockIdx.x * 16 + grp;          // over BATCH*D_INNER
    int b = gidx >> 11, d = gidx & (D_INNER - 1);
    float a = -__expf(A_log[d * D_STATE + lane]);
    float dpar = Dp[d];
    float h = 0.f;
    long tokbase = (long)b * SEQLEN;
    for (int t = 0; t < SEQLEN; ++t) {
        long tok = tokbase + t;
        float dl = delta[tok * D_INNER + d];
        float x  = xb[tok * D_INNER + d];
        float Bn = xpj[tok * XPJ_N + DT_RANK + lane];
        float Cn = xpj[tok * XPJ_N + DT_RANK + D_STATE + lane];
        float dA = __expf(dl * a);
        h = dA * h + dl * Bn * x;
        float p = h * Cn;
        p += __shfl_xor(p, 1);
        p += __shfl_xor(p, 2);
        p += __shfl_xor(p, 4);
        p += __shfl_xor(p, 8);
        if (lane == 0) {
            float y = p + x * dpar;
            float z = xz[tok * NPROJ + D_INNER + d];
            yfin[tok * D_INNER + d] = y * (z * sigmoidf_(z));
        }
    }
}

extern "C" void kernel_launch(void* const* d_in, const int* in_sizes, int n_in,
                              void* d_out, int out_size, void* d_ws, size_t ws_size,
                              hipStream_t stream) {
    const float* x         = (const float*)d_in[0];
    const float* ln_gamma  = (const float*)d_in[1];
    const float* ln_beta   = (const float*)d_in[2];
    const float* in_proj_w = (const float*)d_in[3];
    const float* conv_w    = (const float*)d_in[4];
    const float* conv_b    = (const float*)d_in[5];
    const float* x_proj_w  = (const float*)d_in[6];
    const float* dt_proj_w = (const float*)d_in[7];
    const float* dt_proj_b = (const float*)d_in[8];
    const float* A_log     = (const float*)d_in[9];
    const float* D_param   = (const float*)d_in[10];
    const float* out_proj_w= (const float*)d_in[11];
    float* out = (float*)d_out;

    float* ws = (float*)d_ws;
    float* h     = ws;                               // NTOK*D_MODEL   = 2,097,152
    float* xz    = h     + (long)NTOK * D_MODEL;     // NTOK*NPROJ     = 8,388,608
    float* xb    = xz    + (long)NTOK * NPROJ;       // NTOK*D_INNER   = 4,194,304
    float* xpj   = xb    + (long)NTOK * D_INNER;     // NTOK*XPJ_N     =   327,680
    float* delta = xpj   + (long)NTOK * XPJ_N;       // NTOK*D_INNER
    float* yfin  = delta + (long)NTOK * D_INNER;     // NTOK*D_INNER

    // 1. LayerNorm
    ln_kernel<<<NTOK, 256, 0, stream>>>(x, ln_gamma, ln_beta, h);

    // 2. xz = h @ in_proj_w   [2048,1024]x[1024,4096]
    gemm_kernel<0><<<dim3(NPROJ / 64, NTOK / 64), 256, 0, stream>>>(
        h, D_MODEL, in_proj_w, NPROJ, nullptr, nullptr, xz,
        NTOK, NPROJ, D_MODEL, NPROJ);

    // 3. causal conv4 + bias + SiLU
    conv_silu_kernel<<<(NTOK * D_INNER) / 256, 256, 0, stream>>>(xz, conv_w, conv_b, xb);

    // 4. xpj = xb @ x_proj_w  [2048,2048]x[2048,160]
    gemm_kernel<0><<<dim3((XPJ_N + 63) / 64, NTOK / 64), 256, 0, stream>>>(
        xb, D_INNER, x_proj_w, XPJ_N, nullptr, nullptr, xpj,
        NTOK, XPJ_N, D_INNER, XPJ_N);

    // 5. delta = softplus(dt_r @ dt_proj_w + dt_proj_b)  [2048,128]x[128,2048]
    gemm_kernel<1><<<dim3(D_INNER / 64, NTOK / 64), 256, 0, stream>>>(
        xpj, XPJ_N, dt_proj_w, D_INNER, dt_proj_b, nullptr, delta,
        NTOK, D_INNER, DT_RANK, D_INNER);

    // 6. selective scan + (y + xb*D)*silu(z)
    scan_kernel<<<(BATCH * D_INNER) / 16, 256, 0, stream>>>(
        delta, xb, xpj, xz, A_log, D_param, yfin);

    // 7. out = yfin @ out_proj_w + x, f32 store  [2048,2048]x[2048,1024]
    gemm_kernel<2><<<dim3(D_MODEL / 64, NTOK / 64), 256, 0, stream>>>(
        yfin, D_INNER, out_proj_w, D_MODEL, nullptr, x, out,
        NTOK, D_MODEL, D_INNER, D_MODEL);
}

// Round 3
// 989.242 us; speedup vs baseline: 1.6294x; 1.6294x over previous
//
#include <hip/hip_runtime.h>
#include <hip/hip_bf16.h>

#define D_MODEL 1024
#define D_INNER 2048
#define NPROJ   4096   /* 2*D_INNER */
#define D_STATE 16
#define DT_RANK 128
#define XPJ_N   160    /* DT_RANK + 2*D_STATE */
#define SEQLEN  1024
#define BATCH   2
#define NTOK    2048   /* BATCH*SEQLEN */
#define CHUNK   64
#define NCHUNK  (SEQLEN / CHUNK)   /* 16 */

__device__ __forceinline__ float sigmoidf_(float x) { return 1.f / (1.f + __expf(-x)); }

// ---------------- LayerNorm: one block per row (NTOK rows of D_MODEL) ----------------
__global__ __launch_bounds__(256) void ln_kernel(const float* __restrict__ x,
                                                 const float* __restrict__ g,
                                                 const float* __restrict__ be,
                                                 float* __restrict__ h)
{
    int row = blockIdx.x;
    const float4* xr = (const float4*)(x + (long)row * D_MODEL);
    float4 v = xr[threadIdx.x];
    float s1 = v.x + v.y + v.z + v.w;
    float s2 = v.x*v.x + v.y*v.y + v.z*v.z + v.w*v.w;
    for (int off = 32; off >= 1; off >>= 1) {
        s1 += __shfl_down(s1, off);
        s2 += __shfl_down(s2, off);
    }
    __shared__ float red[8];
    int wid = threadIdx.x >> 6;
    if ((threadIdx.x & 63) == 0) { red[wid] = s1; red[4 + wid] = s2; }
    __syncthreads();
    float mu  = (red[0] + red[1] + red[2] + red[3]) * (1.f / D_MODEL);
    float ex2 = (red[4] + red[5] + red[6] + red[7]) * (1.f / D_MODEL);
    float inv = rsqrtf(ex2 - mu * mu + 1e-5f);
    float4 g4 = ((const float4*)g)[threadIdx.x];
    float4 b4 = ((const float4*)be)[threadIdx.x];
    float4 o;
    o.x = (v.x - mu) * inv * g4.x + b4.x;
    o.y = (v.y - mu) * inv * g4.y + b4.y;
    o.z = (v.z - mu) * inv * g4.z + b4.z;
    o.w = (v.w - mu) * inv * g4.w + b4.w;
    ((float4*)(h + (long)row * D_MODEL))[threadIdx.x] = o;
}

// ---------------- Generic f32 tiled GEMM, C[M,N] = A[M,K(lda)] * B[K,N(ldb)] ----------
// EPI 0: Cf = acc
// EPI 1: Cf = softplus(acc + bias[n])
// EPI 2: Cf = acc + resid[m*N+n]
template <int EPI>
__global__ __launch_bounds__(256) void gemm_kernel(const float* __restrict__ A, int lda,
                                                   const float* __restrict__ B, int ldb,
                                                   const float* __restrict__ bias,
                                                   const float* __restrict__ resid,
                                                   float* __restrict__ Cf,
                                                   int M, int N, int K, int ldc)
{
    __shared__ float As[64][17];
    __shared__ float Bs[16][65];
    int tid = threadIdx.x;
    int tx = tid & 15, ty = tid >> 4;
    int m0 = blockIdx.y * 64, n0 = blockIdx.x * 64;
    float acc[4][4] = {};
    for (int k0 = 0; k0 < K; k0 += 16) {
        #pragma unroll
        for (int i = 0; i < 4; ++i) {
            int idx = tid + i * 256;
            int r = idx >> 4, c = idx & 15;
            As[r][c] = A[(long)(m0 + r) * lda + (k0 + c)];
        }
        #pragma unroll
        for (int i = 0; i < 4; ++i) {
            int idx = tid + i * 256;
            int r = idx >> 6, c = idx & 63;
            int gn = n0 + c;
            Bs[r][c] = (gn < N) ? B[(long)(k0 + r) * ldb + gn] : 0.f;
        }
        __syncthreads();
        #pragma unroll
        for (int kk = 0; kk < 16; ++kk) {
            float a[4], b[4];
            #pragma unroll
            for (int i = 0; i < 4; ++i) a[i] = As[ty * 4 + i][kk];
            #pragma unroll
            for (int j = 0; j < 4; ++j) b[j] = Bs[kk][tx * 4 + j];
            #pragma unroll
            for (int i = 0; i < 4; ++i)
                #pragma unroll
                for (int j = 0; j < 4; ++j) acc[i][j] += a[i] * b[j];
        }
        __syncthreads();
    }
    #pragma unroll
    for (int i = 0; i < 4; ++i) {
        int gm = m0 + ty * 4 + i;
        #pragma unroll
        for (int j = 0; j < 4; ++j) {
            int gn = n0 + tx * 4 + j;
            if (gn >= N) continue;
            float v = acc[i][j];
            if (EPI == 1) {
                v += bias[gn];
                v = (v > 20.f) ? v : log1pf(__expf(v));
                Cf[(long)gm * ldc + gn] = v;
            } else if (EPI == 2) {
                v += resid[(long)gm * N + gn];
                Cf[(long)gm * ldc + gn] = v;
            } else {
                Cf[(long)gm * ldc + gn] = v;
            }
        }
    }
}

// ---------------- depthwise causal conv (width 4) + bias + SiLU ----------------
__global__ __launch_bounds__(256) void conv_silu_kernel(const float* __restrict__ xz,
                                                        const float* __restrict__ cw,
                                                        const float* __restrict__ cb,
                                                        float* __restrict__ xb)
{
    long i = (long)blockIdx.x * 256 + threadIdx.x;  // over NTOK*D_INNER
    int d = (int)(i & (D_INNER - 1));
    long tok = i >> 11;
    int l = (int)(tok & (SEQLEN - 1));
    float w0 = cw[d * 4 + 0], w1 = cw[d * 4 + 1], w2 = cw[d * 4 + 2], w3 = cw[d * 4 + 3];
    float acc = cb[d];
    acc += xz[tok * NPROJ + d] * w3;
    if (l >= 1) acc += xz[(tok - 1) * NPROJ + d] * w2;
    if (l >= 2) acc += xz[(tok - 2) * NPROJ + d] * w1;
    if (l >= 3) acc += xz[(tok - 3) * NPROJ + d] * w0;
    xb[i] = acc * sigmoidf_(acc);
}

// ======================= chunked selective scan =======================
// Linear recurrence h_t = dA_t*h + dBx_t split into NCHUNK chunks of CHUNK steps.
// gidx = (b*NCHUNK + c)*D_INNER + d; one 16-lane group per gidx, lane = state n.

// Phase A: per-chunk partials P = prod(dA), H = partial state with h_init = 0.
__global__ __launch_bounds__(256) void scan_partial_kernel(const float* __restrict__ delta,
                                                           const float* __restrict__ xb,
                                                           const float* __restrict__ xpj,
                                                           const float* __restrict__ A_log,
                                                           float* __restrict__ Pout,
                                                           float* __restrict__ Hout)
{
    int tid = threadIdx.x;
    int lane = tid & 15, grp = tid >> 4;
    long gidx = (long)blockIdx.x * 16 + grp;      // over BATCH*NCHUNK*D_INNER
    int d = (int)(gidx & (D_INNER - 1));
    int c = (int)((gidx >> 11) & (NCHUNK - 1));
    int b = (int)(gidx >> 15);
    float a = -__expf(A_log[d * D_STATE + lane]);
    float P = 1.f, H = 0.f;
    long tok0 = (long)b * SEQLEN + c * CHUNK;
    for (int t = 0; t < CHUNK; ++t) {
        long tok = tok0 + t;
        float dl = delta[tok * D_INNER + d];
        float x  = xb[tok * D_INNER + d];
        float Bn = xpj[tok * XPJ_N + DT_RANK + lane];
        float dA = __expf(dl * a);
        P *= dA;
        H = dA * H + dl * Bn * x;
    }
    long o = gidx * D_STATE + lane;
    Pout[o] = P;
    Hout[o] = H;
}

// Phase B: serial exclusive scan over the NCHUNK chunks per (b,d,n).
__global__ __launch_bounds__(256) void scan_chunkscan_kernel(const float* __restrict__ P,
                                                             const float* __restrict__ H,
                                                             float* __restrict__ hinit)
{
    long i = (long)blockIdx.x * 256 + threadIdx.x;  // over BATCH*D_INNER*D_STATE
    int n = (int)(i & (D_STATE - 1));
    int d = (int)((i >> 4) & (D_INNER - 1));
    int b = (int)(i >> 15);
    float h = 0.f;
    for (int c = 0; c < NCHUNK; ++c) {
        long o = ((((long)b * NCHUNK + c) * D_INNER + d) * D_STATE) + n;
        hinit[o] = h;
        h = P[o] * h + H[o];
    }
}

// Phase C: re-run each chunk with correct init; fused y = (scan+x*D)*silu(z).
__global__ __launch_bounds__(256) void scan_final_kernel(const float* __restrict__ delta,
                                                         const float* __restrict__ xb,
                                                         const float* __restrict__ xpj,
                                                         const float* __restrict__ xz,
                                                         const float* __restrict__ A_log,
                                                         const float* __restrict__ Dp,
                                                         const float* __restrict__ hinit,
                                                         float* __restrict__ yfin)
{
    int tid = threadIdx.x;
    int lane = tid & 15, grp = tid >> 4;
    long gidx = (long)blockIdx.x * 16 + grp;
    int d = (int)(gidx & (D_INNER - 1));
    int c = (int)((gidx >> 11) & (NCHUNK - 1));
    int b = (int)(gidx >> 15);
    float a = -__expf(A_log[d * D_STATE + lane]);
    float dpar = Dp[d];
    float h = hinit[gidx * D_STATE + lane];
    long tok0 = (long)b * SEQLEN + c * CHUNK;
    for (int t = 0; t < CHUNK; ++t) {
        long tok = tok0 + t;
        float dl = delta[tok * D_INNER + d];
        float x  = xb[tok * D_INNER + d];
        float Bn = xpj[tok * XPJ_N + DT_RANK + lane];
        float Cn = xpj[tok * XPJ_N + DT_RANK + D_STATE + lane];
        float dA = __expf(dl * a);
        h = dA * h + dl * Bn * x;
        float p = h * Cn;
        p += __shfl_xor(p, 1);
        p += __shfl_xor(p, 2);
        p += __shfl_xor(p, 4);
        p += __shfl_xor(p, 8);
        if (lane == 0) {
            float y = p + x * dpar;
            float z = xz[tok * NPROJ + D_INNER + d];
            yfin[tok * D_INNER + d] = y * (z * sigmoidf_(z));
        }
    }
}

extern "C" void kernel_launch(void* const* d_in, const int* in_sizes, int n_in,
                              void* d_out, int out_size, void* d_ws, size_t ws_size,
                              hipStream_t stream) {
    const float* x         = (const float*)d_in[0];
    const float* ln_gamma  = (const float*)d_in[1];
    const float* ln_beta   = (const float*)d_in[2];
    const float* in_proj_w = (const float*)d_in[3];
    const float* conv_w    = (const float*)d_in[4];
    const float* conv_b    = (const float*)d_in[5];
    const float* x_proj_w  = (const float*)d_in[6];
    const float* dt_proj_w = (const float*)d_in[7];
    const float* dt_proj_b = (const float*)d_in[8];
    const float* A_log     = (const float*)d_in[9];
    const float* D_param   = (const float*)d_in[10];
    const float* out_proj_w= (const float*)d_in[11];
    float* out = (float*)d_out;

    float* ws = (float*)d_ws;
    float* h     = ws;                               // NTOK*D_MODEL   = 2,097,152
    float* xz    = h     + (long)NTOK * D_MODEL;     // NTOK*NPROJ     = 8,388,608
    float* xb    = xz    + (long)NTOK * NPROJ;       // NTOK*D_INNER   = 4,194,304
    float* xpj   = xb    + (long)NTOK * D_INNER;     // NTOK*XPJ_N     =   327,680
    float* delta = xpj   + (long)NTOK * XPJ_N;       // NTOK*D_INNER
    float* yfin  = delta + (long)NTOK * D_INNER;     // NTOK*D_INNER

    // Scratch aliasing (no extra workspace):
    //  P,H live in yfin's space (dead until phase C), hinit in h's space (dead after gemm2).
    const long PH = (long)BATCH * NCHUNK * D_INNER * D_STATE;  // 1,048,576 floats
    float* Pbuf  = yfin;            // 4 MB
    float* Hbuf  = yfin + PH;       // 4 MB  (yfin region is 16 MB total)
    float* hinit = h;               // 4 MB  (h region is 8 MB)

    // 1. LayerNorm
    ln_kernel<<<NTOK, 256, 0, stream>>>(x, ln_gamma, ln_beta, h);

    // 2. xz = h @ in_proj_w   [2048,1024]x[1024,4096]
    gemm_kernel<0><<<dim3(NPROJ / 64, NTOK / 64), 256, 0, stream>>>(
        h, D_MODEL, in_proj_w, NPROJ, nullptr, nullptr, xz,
        NTOK, NPROJ, D_MODEL, NPROJ);

    // 3. causal conv4 + bias + SiLU
    conv_silu_kernel<<<(NTOK * D_INNER) / 256, 256, 0, stream>>>(xz, conv_w, conv_b, xb);

    // 4. xpj = xb @ x_proj_w  [2048,2048]x[2048,160]
    gemm_kernel<0><<<dim3((XPJ_N + 63) / 64, NTOK / 64), 256, 0, stream>>>(
        xb, D_INNER, x_proj_w, XPJ_N, nullptr, nullptr, xpj,
        NTOK, XPJ_N, D_INNER, XPJ_N);

    // 5. delta = softplus(dt_r @ dt_proj_w + dt_proj_b)  [2048,128]x[128,2048]
    gemm_kernel<1><<<dim3(D_INNER / 64, NTOK / 64), 256, 0, stream>>>(
        xpj, XPJ_N, dt_proj_w, D_INNER, dt_proj_b, nullptr, delta,
        NTOK, D_INNER, DT_RANK, D_INNER);

    // 6. chunked selective scan
    scan_partial_kernel<<<(BATCH * NCHUNK * D_INNER) / 16, 256, 0, stream>>>(
        delta, xb, xpj, A_log, Pbuf, Hbuf);
    scan_chunkscan_kernel<<<(BATCH * D_INNER * D_STATE) / 256, 256, 0, stream>>>(
        Pbuf, Hbuf, hinit);
    scan_final_kernel<<<(BATCH * NCHUNK * D_INNER) / 16, 256, 0, stream>>>(
        delta, xb, xpj, xz, A_log, D_param, hinit, yfin);

    // 7. out = yfin @ out_proj_w + x  [2048,2048]x[2048,1024]
    gemm_kernel<2><<<dim3(D_MODEL / 64, NTOK / 64), 256, 0, stream>>>(
        yfin, D_INNER, out_proj_w, D_MODEL, nullptr, x, out,
        NTOK, D_MODEL, D_INNER, D_MODEL);
}

// Round 4
// 481.237 us; speedup vs baseline: 3.3495x; 2.0556x over previous
//
#include <hip/hip_runtime.h>
#include <hip/hip_bf16.h>

#define D_MODEL 1024
#define D_INNER 2048
#define NPROJ   4096   /* 2*D_INNER */
#define D_STATE 16
#define DT_RANK 128
#define XPJ_N   160    /* DT_RANK + 2*D_STATE */
#define SEQLEN  1024
#define BATCH   2
#define NTOK    2048   /* BATCH*SEQLEN */
#define CHUNK   64
#define NCHUNK  (SEQLEN / CHUNK)   /* 16 */

typedef short short8 __attribute__((ext_vector_type(8)));
typedef float f32x4 __attribute__((ext_vector_type(4)));

__device__ __forceinline__ float sigmoidf_(float x) { return 1.f / (1.f + __expf(-x)); }
__device__ __forceinline__ ushort f2bf_bits(float f) {
    __hip_bfloat16 h = __float2bfloat16(f);
    return *(ushort*)&h;
}

// ---------------- LayerNorm → bf16 output ----------------
__global__ __launch_bounds__(256) void ln_kernel(const float* __restrict__ x,
                                                 const float* __restrict__ g,
                                                 const float* __restrict__ be,
                                                 ushort* __restrict__ hb)
{
    int row = blockIdx.x;
    const float4* xr = (const float4*)(x + (long)row * D_MODEL);
    float4 v = xr[threadIdx.x];
    float s1 = v.x + v.y + v.z + v.w;
    float s2 = v.x*v.x + v.y*v.y + v.z*v.z + v.w*v.w;
    for (int off = 32; off >= 1; off >>= 1) {
        s1 += __shfl_down(s1, off);
        s2 += __shfl_down(s2, off);
    }
    __shared__ float red[8];
    int wid = threadIdx.x >> 6;
    if ((threadIdx.x & 63) == 0) { red[wid] = s1; red[4 + wid] = s2; }
    __syncthreads();
    float mu  = (red[0] + red[1] + red[2] + red[3]) * (1.f / D_MODEL);
    float ex2 = (red[4] + red[5] + red[6] + red[7]) * (1.f / D_MODEL);
    float inv = rsqrtf(ex2 - mu * mu + 1e-5f);
    float4 g4 = ((const float4*)g)[threadIdx.x];
    float4 b4 = ((const float4*)be)[threadIdx.x];
    ushort4 o;
    o.x = f2bf_bits((v.x - mu) * inv * g4.x + b4.x);
    o.y = f2bf_bits((v.y - mu) * inv * g4.y + b4.y);
    o.z = f2bf_bits((v.z - mu) * inv * g4.z + b4.z);
    o.w = f2bf_bits((v.w - mu) * inv * g4.w + b4.w);
    *(ushort4*)(hb + (long)row * D_MODEL + threadIdx.x * 4) = o;
}

// ---------------- f32 [R][C] → bf16 [C][R] transpose ----------------
__global__ __launch_bounds__(256) void transpose_bf16_kernel(const float* __restrict__ in,
                                                             ushort* __restrict__ out,
                                                             int R, int C)
{
    __shared__ float tile[64][65];
    int c0 = blockIdx.x * 64, r0 = blockIdx.y * 64;
    #pragma unroll
    for (int i = 0; i < 16; ++i) {
        int idx = threadIdx.x + i * 256;
        int r = idx >> 6, c = idx & 63;
        tile[r][c] = in[(long)(r0 + r) * C + (c0 + c)];
    }
    __syncthreads();
    #pragma unroll
    for (int i = 0; i < 16; ++i) {
        int idx = threadIdx.x + i * 256;
        int cc = idx >> 6, rr = idx & 63;
        out[(long)(c0 + cc) * R + (r0 + rr)] = f2bf_bits(tile[rr][cc]);
    }
}

// ---------------- bf16 MFMA GEMM: C[M,N] = A[M,K] * Bt[N,K]^T ----------------
// 128x128 tile, BK=32, 4 waves (2x2 of 64x64), 16x16x32 MFMA, global_load_lds staging
// with kg XOR-swizzle (both-sides) for conflict-free ds_read_b128.
// EPI 0: C = acc ; EPI 2: C = acc + resid
template <int EPI>
__global__ __launch_bounds__(256) void gemm_mfma_kernel(const ushort* __restrict__ A,
                                                        const ushort* __restrict__ Bt,
                                                        const float* __restrict__ resid,
                                                        float* __restrict__ C,
                                                        int M, int N, int K)
{
    __shared__ __align__(16) ushort Al[128 * 32];
    __shared__ __align__(16) ushort Bl[128 * 32];
    int tid = threadIdx.x;
    int lane = tid & 63;
    int w = tid >> 6, wr = w >> 1, wc = w & 1;
    int m0 = blockIdx.y * 128, n0 = blockIdx.x * 128;
    f32x4 acc[4][4];
    #pragma unroll
    for (int m = 0; m < 4; ++m)
        #pragma unroll
        for (int n = 0; n < 4; ++n) acc[m][n] = (f32x4){0.f, 0.f, 0.f, 0.f};
    int l15 = lane & 15, kq = lane >> 4;

    for (int k0 = 0; k0 < K; k0 += 32) {
        #pragma unroll
        for (int i = 0; i < 2; ++i) {
            int s = i * 256 + tid;
            int row = s >> 2, kg = s & 3;
            int kgl = kg ^ ((row >> 1) & 3);   // pre-swizzled global source (rule #21)
            __builtin_amdgcn_global_load_lds(
                (const __attribute__((address_space(1))) void*)(A + (long)(m0 + row) * K + k0 + kgl * 8),
                (__attribute__((address_space(3))) void*)(Al + s * 8), 16, 0, 0);
            __builtin_amdgcn_global_load_lds(
                (const __attribute__((address_space(1))) void*)(Bt + (long)(n0 + row) * K + k0 + kgl * 8),
                (__attribute__((address_space(3))) void*)(Bl + s * 8), 16, 0, 0);
        }
        __syncthreads();
        short8 af[4], bf[4];
        #pragma unroll
        for (int m = 0; m < 4; ++m) {
            int row = wr * 64 + m * 16 + l15;
            af[m] = *(const short8*)&Al[row * 32 + (kq ^ ((row >> 1) & 3)) * 8];
        }
        #pragma unroll
        for (int n = 0; n < 4; ++n) {
            int row = wc * 64 + n * 16 + l15;
            bf[n] = *(const short8*)&Bl[row * 32 + (kq ^ ((row >> 1) & 3)) * 8];
        }
        #pragma unroll
        for (int m = 0; m < 4; ++m)
            #pragma unroll
            for (int n = 0; n < 4; ++n)
                acc[m][n] = __builtin_amdgcn_mfma_f32_16x16x32_bf16(af[m], bf[n], acc[m][n], 0, 0, 0);
        __syncthreads();
    }
    #pragma unroll
    for (int m = 0; m < 4; ++m) {
        #pragma unroll
        for (int n = 0; n < 4; ++n) {
            #pragma unroll
            for (int r = 0; r < 4; ++r) {
                int row = m0 + wr * 64 + m * 16 + kq * 4 + r;
                int col = n0 + wc * 64 + n * 16 + l15;
                float v = acc[m][n][r];
                if (EPI == 2) v += resid[(long)row * N + col];
                C[(long)row * N + col] = v;
            }
        }
    }
}

// ---------------- Generic f32 tiled GEMM (kept for gemm4 / gemm5) ----------
// EPI 0: Cf = acc ; EPI 1: Cf = softplus(acc + bias[n])
template <int EPI>
__global__ __launch_bounds__(256) void gemm_kernel(const float* __restrict__ A, int lda,
                                                   const float* __restrict__ B, int ldb,
                                                   const float* __restrict__ bias,
                                                   float* __restrict__ Cf,
                                                   int M, int N, int K, int ldc)
{
    __shared__ float As[64][17];
    __shared__ float Bs[16][65];
    int tid = threadIdx.x;
    int tx = tid & 15, ty = tid >> 4;
    int m0 = blockIdx.y * 64, n0 = blockIdx.x * 64;
    float acc[4][4] = {};
    for (int k0 = 0; k0 < K; k0 += 16) {
        #pragma unroll
        for (int i = 0; i < 4; ++i) {
            int idx = tid + i * 256;
            int r = idx >> 4, c = idx & 15;
            As[r][c] = A[(long)(m0 + r) * lda + (k0 + c)];
        }
        #pragma unroll
        for (int i = 0; i < 4; ++i) {
            int idx = tid + i * 256;
            int r = idx >> 6, c = idx & 63;
            int gn = n0 + c;
            Bs[r][c] = (gn < N) ? B[(long)(k0 + r) * ldb + gn] : 0.f;
        }
        __syncthreads();
        #pragma unroll
        for (int kk = 0; kk < 16; ++kk) {
            float a[4], b[4];
            #pragma unroll
            for (int i = 0; i < 4; ++i) a[i] = As[ty * 4 + i][kk];
            #pragma unroll
            for (int j = 0; j < 4; ++j) b[j] = Bs[kk][tx * 4 + j];
            #pragma unroll
            for (int i = 0; i < 4; ++i)
                #pragma unroll
                for (int j = 0; j < 4; ++j) acc[i][j] += a[i] * b[j];
        }
        __syncthreads();
    }
    #pragma unroll
    for (int i = 0; i < 4; ++i) {
        int gm = m0 + ty * 4 + i;
        #pragma unroll
        for (int j = 0; j < 4; ++j) {
            int gn = n0 + tx * 4 + j;
            if (gn >= N) continue;
            float v = acc[i][j];
            if (EPI == 1) {
                v += bias[gn];
                v = (v > 20.f) ? v : log1pf(__expf(v));
            }
            Cf[(long)gm * ldc + gn] = v;
        }
    }
}

// ---------------- depthwise causal conv (width 4) + bias + SiLU ----------------
__global__ __launch_bounds__(256) void conv_silu_kernel(const float* __restrict__ xz,
                                                        const float* __restrict__ cw,
                                                        const float* __restrict__ cb,
                                                        float* __restrict__ xb)
{
    long i = (long)blockIdx.x * 256 + threadIdx.x;  // over NTOK*D_INNER
    int d = (int)(i & (D_INNER - 1));
    long tok = i >> 11;
    int l = (int)(tok & (SEQLEN - 1));
    float w0 = cw[d * 4 + 0], w1 = cw[d * 4 + 1], w2 = cw[d * 4 + 2], w3 = cw[d * 4 + 3];
    float acc = cb[d];
    acc += xz[tok * NPROJ + d] * w3;
    if (l >= 1) acc += xz[(tok - 1) * NPROJ + d] * w2;
    if (l >= 2) acc += xz[(tok - 2) * NPROJ + d] * w1;
    if (l >= 3) acc += xz[(tok - 3) * NPROJ + d] * w0;
    xb[i] = acc * sigmoidf_(acc);
}

// ======================= chunked selective scan =======================
__global__ __launch_bounds__(256) void scan_partial_kernel(const float* __restrict__ delta,
                                                           const float* __restrict__ xb,
                                                           const float* __restrict__ xpj,
                                                           const float* __restrict__ A_log,
                                                           float* __restrict__ Pout,
                                                           float* __restrict__ Hout)
{
    int tid = threadIdx.x;
    int lane = tid & 15, grp = tid >> 4;
    long gidx = (long)blockIdx.x * 16 + grp;      // over BATCH*NCHUNK*D_INNER
    int d = (int)(gidx & (D_INNER - 1));
    int c = (int)((gidx >> 11) & (NCHUNK - 1));
    int b = (int)(gidx >> 15);
    float a = -__expf(A_log[d * D_STATE + lane]);
    float P = 1.f, H = 0.f;
    long tok0 = (long)b * SEQLEN + c * CHUNK;
    for (int t = 0; t < CHUNK; ++t) {
        long tok = tok0 + t;
        float dl = delta[tok * D_INNER + d];
        float x  = xb[tok * D_INNER + d];
        float Bn = xpj[tok * XPJ_N + DT_RANK + lane];
        float dA = __expf(dl * a);
        P *= dA;
        H = dA * H + dl * Bn * x;
    }
    long o = gidx * D_STATE + lane;
    Pout[o] = P;
    Hout[o] = H;
}

__global__ __launch_bounds__(256) void scan_chunkscan_kernel(const float* __restrict__ P,
                                                             const float* __restrict__ H,
                                                             float* __restrict__ hinit)
{
    long i = (long)blockIdx.x * 256 + threadIdx.x;  // over BATCH*D_INNER*D_STATE
    int n = (int)(i & (D_STATE - 1));
    int d = (int)((i >> 4) & (D_INNER - 1));
    int b = (int)(i >> 15);
    float h = 0.f;
    for (int c = 0; c < NCHUNK; ++c) {
        long o = ((((long)b * NCHUNK + c) * D_INNER + d) * D_STATE) + n;
        hinit[o] = h;
        h = P[o] * h + H[o];
    }
}

// Phase C: re-run each chunk with correct init; y=(scan+x*D)*silu(z), bf16 out.
__global__ __launch_bounds__(256) void scan_final_kernel(const float* __restrict__ delta,
                                                         const float* __restrict__ xb,
                                                         const float* __restrict__ xpj,
                                                         const float* __restrict__ xz,
                                                         const float* __restrict__ A_log,
                                                         const float* __restrict__ Dp,
                                                         const float* __restrict__ hinit,
                                                         ushort* __restrict__ yb)
{
    int tid = threadIdx.x;
    int lane = tid & 15, grp = tid >> 4;
    long gidx = (long)blockIdx.x * 16 + grp;
    int d = (int)(gidx & (D_INNER - 1));
    int c = (int)((gidx >> 11) & (NCHUNK - 1));
    int b = (int)(gidx >> 15);
    float a = -__expf(A_log[d * D_STATE + lane]);
    float dpar = Dp[d];
    float h = hinit[gidx * D_STATE + lane];
    long tok0 = (long)b * SEQLEN + c * CHUNK;
    for (int t = 0; t < CHUNK; ++t) {
        long tok = tok0 + t;
        float dl = delta[tok * D_INNER + d];
        float x  = xb[tok * D_INNER + d];
        float Bn = xpj[tok * XPJ_N + DT_RANK + lane];
        float Cn = xpj[tok * XPJ_N + DT_RANK + D_STATE + lane];
        float dA = __expf(dl * a);
        h = dA * h + dl * Bn * x;
        float p = h * Cn;
        p += __shfl_xor(p, 1);
        p += __shfl_xor(p, 2);
        p += __shfl_xor(p, 4);
        p += __shfl_xor(p, 8);
        if (lane == 0) {
            float y = p + x * dpar;
            float z = xz[tok * NPROJ + D_INNER + d];
            yb[tok * D_INNER + d] = f2bf_bits(y * (z * sigmoidf_(z)));
        }
    }
}

extern "C" void kernel_launch(void* const* d_in, const int* in_sizes, int n_in,
                              void* d_out, int out_size, void* d_ws, size_t ws_size,
                              hipStream_t stream) {
    const float* x         = (const float*)d_in[0];
    const float* ln_gamma  = (const float*)d_in[1];
    const float* ln_beta   = (const float*)d_in[2];
    const float* in_proj_w = (const float*)d_in[3];
    const float* conv_w    = (const float*)d_in[4];
    const float* conv_b    = (const float*)d_in[5];
    const float* x_proj_w  = (const float*)d_in[6];
    const float* dt_proj_w = (const float*)d_in[7];
    const float* dt_proj_b = (const float*)d_in[8];
    const float* A_log     = (const float*)d_in[9];
    const float* D_param   = (const float*)d_in[10];
    const float* out_proj_w= (const float*)d_in[11];
    float* out = (float*)d_out;

    float* ws = (float*)d_ws;
    float* h     = ws;                               // 2,097,152 floats
    float* xz    = h     + (long)NTOK * D_MODEL;     // 8,388,608
    float* xb    = xz    + (long)NTOK * NPROJ;       // 4,194,304
    float* xpj   = xb    + (long)NTOK * D_INNER;     //   327,680
    float* delta = xpj   + (long)NTOK * XPJ_N;       // 4,194,304
    float* yfin  = delta + (long)NTOK * D_INNER;     // 4,194,304

    // Aliased scratch (all within existing 93.6 MB footprint):
    const long PH = (long)BATCH * NCHUNK * D_INNER * D_STATE;   // 1,048,576 floats
    ushort* h_bf16 = (ushort*)h;                 // 4.2 MB in h slot (h f32 never materialized)
    float*  hinit  = h + PH;                     // second half of h slot (dead until phase B)
    ushort* W2T    = (ushort*)xb;                // 8.4 MB in xb slot (dead until conv)
    float*  Pbuf   = yfin;                       // 4 MB
    float*  Hbuf   = yfin + PH;                  // 4 MB
    ushort* y_bf16 = (ushort*)(yfin + 2 * PH);   // 8.4 MB, disjoint from P/H
    ushort* W7T    = (ushort*)xz;                // 4 MB in xz slot (dead after scan_final)

    // 0a. W2T = in_proj_w^T bf16  [4096][1024]
    transpose_bf16_kernel<<<dim3(NPROJ / 64, D_MODEL / 64), 256, 0, stream>>>(
        in_proj_w, W2T, D_MODEL, NPROJ);

    // 1. LayerNorm → bf16
    ln_kernel<<<NTOK, 256, 0, stream>>>(x, ln_gamma, ln_beta, h_bf16);

    // 2. xz = h @ in_proj_w  (MFMA)  [2048,1024]x[1024,4096]
    gemm_mfma_kernel<0><<<dim3(NPROJ / 128, NTOK / 128), 256, 0, stream>>>(
        h_bf16, W2T, nullptr, xz, NTOK, NPROJ, D_MODEL);

    // 3. causal conv4 + bias + SiLU (overwrites W2T region — W2T dead)
    conv_silu_kernel<<<(NTOK * D_INNER) / 256, 256, 0, stream>>>(xz, conv_w, conv_b, xb);

    // 4. xpj = xb @ x_proj_w  [2048,2048]x[2048,160]  (f32)
    gemm_kernel<0><<<dim3((XPJ_N + 63) / 64, NTOK / 64), 256, 0, stream>>>(
        xb, D_INNER, x_proj_w, XPJ_N, nullptr, xpj,
        NTOK, XPJ_N, D_INNER, XPJ_N);

    // 5. delta = softplus(dt_r @ dt_proj_w + b)  [2048,128]x[128,2048]  (f32)
    gemm_kernel<1><<<dim3(D_INNER / 64, NTOK / 64), 256, 0, stream>>>(
        xpj, XPJ_N, dt_proj_w, D_INNER, dt_proj_b, delta,
        NTOK, D_INNER, DT_RANK, D_INNER);

    // 6. chunked selective scan (phase C writes bf16)
    scan_partial_kernel<<<(BATCH * NCHUNK * D_INNER) / 16, 256, 0, stream>>>(
        delta, xb, xpj, A_log, Pbuf, Hbuf);
    scan_chunkscan_kernel<<<(BATCH * D_INNER * D_STATE) / 256, 256, 0, stream>>>(
        Pbuf, Hbuf, hinit);
    scan_final_kernel<<<(BATCH * NCHUNK * D_INNER) / 16, 256, 0, stream>>>(
        delta, xb, xpj, xz, A_log, D_param, hinit, y_bf16);

    // 6b. W7T = out_proj_w^T bf16 [1024][2048] (xz now dead)
    transpose_bf16_kernel<<<dim3(D_MODEL / 64, D_INNER / 64), 256, 0, stream>>>(
        out_proj_w, W7T, D_INNER, D_MODEL);

    // 7. out = yfin @ out_proj_w + x  (MFMA)  [2048,2048]x[2048,1024]
    gemm_mfma_kernel<2><<<dim3(D_MODEL / 128, NTOK / 128), 256, 0, stream>>>(
        y_bf16, W7T, x, out, NTOK, D_MODEL, D_INNER);
}

// Round 5
// 307.680 us; speedup vs baseline: 5.2389x; 1.5641x over previous
//
#include <hip/hip_runtime.h>
#include <hip/hip_bf16.h>

#define D_MODEL 1024
#define D_INNER 2048
#define NPROJ   4096   /* 2*D_INNER */
#define D_STATE 16
#define DT_RANK 128
#define XPJ_N   160    /* DT_RANK + 2*D_STATE */
#define SEQLEN  1024
#define BATCH   2
#define NTOK    2048   /* BATCH*SEQLEN */
#define CHUNK   64
#define NCHUNK  (SEQLEN / CHUNK)   /* 16 */
#define SPLITK  8

typedef short short8 __attribute__((ext_vector_type(8)));
typedef float f32x4 __attribute__((ext_vector_type(4)));

__device__ __forceinline__ float sigmoidf_(float x) { return 1.f / (1.f + __expf(-x)); }
__device__ __forceinline__ ushort f2bf_bits(float f) {
    __hip_bfloat16 h = __float2bfloat16(f);
    return *(ushort*)&h;
}

// ---------------- LayerNorm → bf16 output ----------------
__global__ __launch_bounds__(256) void ln_kernel(const float* __restrict__ x,
                                                 const float* __restrict__ g,
                                                 const float* __restrict__ be,
                                                 ushort* __restrict__ hb)
{
    int row = blockIdx.x;
    const float4* xr = (const float4*)(x + (long)row * D_MODEL);
    float4 v = xr[threadIdx.x];
    float s1 = v.x + v.y + v.z + v.w;
    float s2 = v.x*v.x + v.y*v.y + v.z*v.z + v.w*v.w;
    for (int off = 32; off >= 1; off >>= 1) {
        s1 += __shfl_down(s1, off);
        s2 += __shfl_down(s2, off);
    }
    __shared__ float red[8];
    int wid = threadIdx.x >> 6;
    if ((threadIdx.x & 63) == 0) { red[wid] = s1; red[4 + wid] = s2; }
    __syncthreads();
    float mu  = (red[0] + red[1] + red[2] + red[3]) * (1.f / D_MODEL);
    float ex2 = (red[4] + red[5] + red[6] + red[7]) * (1.f / D_MODEL);
    float inv = rsqrtf(ex2 - mu * mu + 1e-5f);
    float4 g4 = ((const float4*)g)[threadIdx.x];
    float4 b4 = ((const float4*)be)[threadIdx.x];
    ushort4 o;
    o.x = f2bf_bits((v.x - mu) * inv * g4.x + b4.x);
    o.y = f2bf_bits((v.y - mu) * inv * g4.y + b4.y);
    o.z = f2bf_bits((v.z - mu) * inv * g4.z + b4.z);
    o.w = f2bf_bits((v.w - mu) * inv * g4.w + b4.w);
    *(ushort4*)(hb + (long)row * D_MODEL + threadIdx.x * 4) = o;
}

// ---------------- f32 [R][C] → bf16 [C][R] transpose (guarded) ----------------
__global__ __launch_bounds__(256) void transpose_bf16_kernel(const float* __restrict__ in,
                                                             ushort* __restrict__ out,
                                                             int R, int C)
{
    __shared__ float tile[64][65];
    int c0 = blockIdx.x * 64, r0 = blockIdx.y * 64;
    #pragma unroll
    for (int i = 0; i < 16; ++i) {
        int idx = threadIdx.x + i * 256;
        int r = idx >> 6, c = idx & 63;
        tile[r][c] = (r0 + r < R && c0 + c < C) ? in[(long)(r0 + r) * C + (c0 + c)] : 0.f;
    }
    __syncthreads();
    #pragma unroll
    for (int i = 0; i < 16; ++i) {
        int idx = threadIdx.x + i * 256;
        int cc = idx >> 6, rr = idx & 63;
        if (c0 + cc < C && r0 + rr < R)
            out[(long)(c0 + cc) * R + (r0 + rr)] = f2bf_bits(tile[rr][cc]);
    }
}

// ---------------- bf16 MFMA GEMM: C[M,N] = A[M,K] * Bt[N,K]^T ----------------
// 128x128 tile, BK=32, 4 waves (2x2 of 64x64), 16x16x32 MFMA, global_load_lds staging
// with kg XOR-swizzle (both-sides).
// EPI 0: C = acc ; EPI 1: C = softplus(acc + bias[n]) ; EPI 2: C = acc + resid
template <int EPI>
__global__ __launch_bounds__(256) void gemm_mfma_kernel(const ushort* __restrict__ A,
                                                        const ushort* __restrict__ Bt,
                                                        const float* __restrict__ bias,
                                                        const float* __restrict__ resid,
                                                        float* __restrict__ C,
                                                        int M, int N, int K)
{
    __shared__ __align__(16) ushort Al[128 * 32];
    __shared__ __align__(16) ushort Bl[128 * 32];
    int tid = threadIdx.x;
    int lane = tid & 63;
    int w = tid >> 6, wr = w >> 1, wc = w & 1;
    int m0 = blockIdx.y * 128, n0 = blockIdx.x * 128;
    f32x4 acc[4][4];
    #pragma unroll
    for (int m = 0; m < 4; ++m)
        #pragma unroll
        for (int n = 0; n < 4; ++n) acc[m][n] = (f32x4){0.f, 0.f, 0.f, 0.f};
    int l15 = lane & 15, kq = lane >> 4;

    for (int k0 = 0; k0 < K; k0 += 32) {
        #pragma unroll
        for (int i = 0; i < 2; ++i) {
            int s = i * 256 + tid;
            int row = s >> 2, kg = s & 3;
            int kgl = kg ^ ((row >> 1) & 3);
            __builtin_amdgcn_global_load_lds(
                (const __attribute__((address_space(1))) void*)(A + (long)(m0 + row) * K + k0 + kgl * 8),
                (__attribute__((address_space(3))) void*)(Al + s * 8), 16, 0, 0);
            __builtin_amdgcn_global_load_lds(
                (const __attribute__((address_space(1))) void*)(Bt + (long)(n0 + row) * K + k0 + kgl * 8),
                (__attribute__((address_space(3))) void*)(Bl + s * 8), 16, 0, 0);
        }
        __syncthreads();
        short8 af[4], bf[4];
        #pragma unroll
        for (int m = 0; m < 4; ++m) {
            int row = wr * 64 + m * 16 + l15;
            af[m] = *(const short8*)&Al[row * 32 + (kq ^ ((row >> 1) & 3)) * 8];
        }
        #pragma unroll
        for (int n = 0; n < 4; ++n) {
            int row = wc * 64 + n * 16 + l15;
            bf[n] = *(const short8*)&Bl[row * 32 + (kq ^ ((row >> 1) & 3)) * 8];
        }
        #pragma unroll
        for (int m = 0; m < 4; ++m)
            #pragma unroll
            for (int n = 0; n < 4; ++n)
                acc[m][n] = __builtin_amdgcn_mfma_f32_16x16x32_bf16(af[m], bf[n], acc[m][n], 0, 0, 0);
        __syncthreads();
    }
    #pragma unroll
    for (int m = 0; m < 4; ++m) {
        #pragma unroll
        for (int n = 0; n < 4; ++n) {
            #pragma unroll
            for (int r = 0; r < 4; ++r) {
                int row = m0 + wr * 64 + m * 16 + kq * 4 + r;
                int col = n0 + wc * 64 + n * 16 + l15;
                float v = acc[m][n][r];
                if (EPI == 1) {
                    v += bias[col];
                    v = (v > 20.f) ? v : log1pf(__expf(v));
                } else if (EPI == 2) {
                    v += resid[(long)row * N + col];
                }
                C[(long)row * N + col] = v;
            }
        }
    }
}

// -------- split-K bf16 MFMA GEMM for xpj: Ppart[sk] = A[M,K-slice] * Bt[160,K]^T --------
// BM=64, BN=160 (full), BK=32; 4 waves 2x2 (32 rows x 80 cols each; 2x5 frags).
__global__ __launch_bounds__(256) void gemm4_mfma_kernel(const ushort* __restrict__ A,
                                                         const ushort* __restrict__ Bt,
                                                         float* __restrict__ Ppart,
                                                         int M, int K)
{
    __shared__ __align__(16) ushort Al[64 * 32];    // 4 KB
    __shared__ __align__(16) ushort Bl[160 * 32];   // 10 KB
    int tid = threadIdx.x;
    int lane = tid & 63;
    int w = tid >> 6, wr = w >> 1, wc = w & 1;
    int sk = blockIdx.x;
    int m0 = blockIdx.y * 64;
    int kbase = sk * (K / SPLITK);
    f32x4 acc[2][5];
    #pragma unroll
    for (int m = 0; m < 2; ++m)
        #pragma unroll
        for (int n = 0; n < 5; ++n) acc[m][n] = (f32x4){0.f, 0.f, 0.f, 0.f};
    int l15 = lane & 15, kq = lane >> 4;

    for (int ks = 0; ks < K / SPLITK; ks += 32) {
        int k0 = kbase + ks;
        {   // A: 64 rows x 4 kg slots = 256 x 16B
            int s = tid;
            int row = s >> 2, kg = s & 3;
            int kgl = kg ^ ((row >> 1) & 3);
            __builtin_amdgcn_global_load_lds(
                (const __attribute__((address_space(1))) void*)(A + (long)(m0 + row) * K + k0 + kgl * 8),
                (__attribute__((address_space(3))) void*)(Al + s * 8), 16, 0, 0);
        }
        #pragma unroll
        for (int i = 0; i < 3; ++i) {   // B: 160 rows x 4 = 640 x 16B
            int s = i * 256 + tid;
            if (s < 640) {
                int row = s >> 2, kg = s & 3;
                int kgl = kg ^ ((row >> 1) & 3);
                __builtin_amdgcn_global_load_lds(
                    (const __attribute__((address_space(1))) void*)(Bt + (long)row * K + k0 + kgl * 8),
                    (__attribute__((address_space(3))) void*)(Bl + s * 8), 16, 0, 0);
            }
        }
        __syncthreads();
        short8 af[2], bf[5];
        #pragma unroll
        for (int m = 0; m < 2; ++m) {
            int row = wr * 32 + m * 16 + l15;
            af[m] = *(const short8*)&Al[row * 32 + (kq ^ ((row >> 1) & 3)) * 8];
        }
        #pragma unroll
        for (int n = 0; n < 5; ++n) {
            int row = wc * 80 + n * 16 + l15;
            bf[n] = *(const short8*)&Bl[row * 32 + (kq ^ ((row >> 1) & 3)) * 8];
        }
        #pragma unroll
        for (int m = 0; m < 2; ++m)
            #pragma unroll
            for (int n = 0; n < 5; ++n)
                acc[m][n] = __builtin_amdgcn_mfma_f32_16x16x32_bf16(af[m], bf[n], acc[m][n], 0, 0, 0);
        __syncthreads();
    }
    float* P = Ppart + (long)sk * M * XPJ_N;
    #pragma unroll
    for (int m = 0; m < 2; ++m) {
        #pragma unroll
        for (int n = 0; n < 5; ++n) {
            #pragma unroll
            for (int r = 0; r < 4; ++r) {
                int row = m0 + wr * 32 + m * 16 + kq * 4 + r;
                int col = wc * 80 + n * 16 + l15;
                P[(long)row * XPJ_N + col] = acc[m][n][r];
            }
        }
    }
}

// -------- reduce split-K partials → xpj f32 + dt_r bf16 --------
__global__ __launch_bounds__(256) void reduce_xpj_kernel(const float* __restrict__ Ppart,
                                                         float* __restrict__ xpj,
                                                         ushort* __restrict__ dtr)
{
    long i = (long)blockIdx.x * 256 + threadIdx.x;   // over NTOK*XPJ_N
    float s = 0.f;
    #pragma unroll
    for (int k = 0; k < SPLITK; ++k) s += Ppart[k * (long)NTOK * XPJ_N + i];
    xpj[i] = s;
    int col = (int)(i % XPJ_N);
    long row = i / XPJ_N;
    if (col < DT_RANK) dtr[row * DT_RANK + col] = f2bf_bits(s);
}

// ---------------- depthwise causal conv (width 4) + bias + SiLU; f32 + bf16 out -------
__global__ __launch_bounds__(256) void conv_silu_kernel(const float* __restrict__ xz,
                                                        const float* __restrict__ cw,
                                                        const float* __restrict__ cb,
                                                        float* __restrict__ xb,
                                                        ushort* __restrict__ xbb)
{
    long i = (long)blockIdx.x * 256 + threadIdx.x;  // over NTOK*D_INNER
    int d = (int)(i & (D_INNER - 1));
    long tok = i >> 11;
    int l = (int)(tok & (SEQLEN - 1));
    float w0 = cw[d * 4 + 0], w1 = cw[d * 4 + 1], w2 = cw[d * 4 + 2], w3 = cw[d * 4 + 3];
    float acc = cb[d];
    acc += xz[tok * NPROJ + d] * w3;
    if (l >= 1) acc += xz[(tok - 1) * NPROJ + d] * w2;
    if (l >= 2) acc += xz[(tok - 2) * NPROJ + d] * w1;
    if (l >= 3) acc += xz[(tok - 3) * NPROJ + d] * w0;
    float v = acc * sigmoidf_(acc);
    xb[i] = v;
    xbb[i] = f2bf_bits(v);
}

// ======================= chunked selective scan =======================
__global__ __launch_bounds__(256) void scan_partial_kernel(const float* __restrict__ delta,
                                                           const float* __restrict__ xb,
                                                           const float* __restrict__ xpj,
                                                           const float* __restrict__ A_log,
                                                           float* __restrict__ Pout,
                                                           float* __restrict__ Hout)
{
    int tid = threadIdx.x;
    int lane = tid & 15, grp = tid >> 4;
    long gidx = (long)blockIdx.x * 16 + grp;      // over BATCH*NCHUNK*D_INNER
    int d = (int)(gidx & (D_INNER - 1));
    int c = (int)((gidx >> 11) & (NCHUNK - 1));
    int b = (int)(gidx >> 15);
    float a = -__expf(A_log[d * D_STATE + lane]);
    float P = 1.f, H = 0.f;
    long tok0 = (long)b * SEQLEN + c * CHUNK;
    for (int t = 0; t < CHUNK; ++t) {
        long tok = tok0 + t;
        float dl = delta[tok * D_INNER + d];
        float x  = xb[tok * D_INNER + d];
        float Bn = xpj[tok * XPJ_N + DT_RANK + lane];
        float dA = __expf(dl * a);
        P *= dA;
        H = dA * H + dl * Bn * x;
    }
    long o = gidx * D_STATE + lane;
    Pout[o] = P;
    Hout[o] = H;
}

__global__ __launch_bounds__(256) void scan_chunkscan_kernel(const float* __restrict__ P,
                                                             const float* __restrict__ H,
                                                             float* __restrict__ hinit)
{
    long i = (long)blockIdx.x * 256 + threadIdx.x;  // over BATCH*D_INNER*D_STATE
    int n = (int)(i & (D_STATE - 1));
    int d = (int)((i >> 4) & (D_INNER - 1));
    int b = (int)(i >> 15);
    float h = 0.f;
    for (int c = 0; c < NCHUNK; ++c) {
        long o = ((((long)b * NCHUNK + c) * D_INNER + d) * D_STATE) + n;
        hinit[o] = h;
        h = P[o] * h + H[o];
    }
}

__global__ __launch_bounds__(256) void scan_final_kernel(const float* __restrict__ delta,
                                                         const float* __restrict__ xb,
                                                         const float* __restrict__ xpj,
                                                         const float* __restrict__ xz,
                                                         const float* __restrict__ A_log,
                                                         const float* __restrict__ Dp,
                                                         const float* __restrict__ hinit,
                                                         ushort* __restrict__ yb)
{
    int tid = threadIdx.x;
    int lane = tid & 15, grp = tid >> 4;
    long gidx = (long)blockIdx.x * 16 + grp;
    int d = (int)(gidx & (D_INNER - 1));
    int c = (int)((gidx >> 11) & (NCHUNK - 1));
    int b = (int)(gidx >> 15);
    float a = -__expf(A_log[d * D_STATE + lane]);
    float dpar = Dp[d];
    float h = hinit[gidx * D_STATE + lane];
    long tok0 = (long)b * SEQLEN + c * CHUNK;
    for (int t = 0; t < CHUNK; ++t) {
        long tok = tok0 + t;
        float dl = delta[tok * D_INNER + d];
        float x  = xb[tok * D_INNER + d];
        float Bn = xpj[tok * XPJ_N + DT_RANK + lane];
        float Cn = xpj[tok * XPJ_N + DT_RANK + D_STATE + lane];
        float dA = __expf(dl * a);
        h = dA * h + dl * Bn * x;
        float p = h * Cn;
        p += __shfl_xor(p, 1);
        p += __shfl_xor(p, 2);
        p += __shfl_xor(p, 4);
        p += __shfl_xor(p, 8);
        if (lane == 0) {
            float y = p + x * dpar;
            float z = xz[tok * NPROJ + D_INNER + d];
            yb[tok * D_INNER + d] = f2bf_bits(y * (z * sigmoidf_(z)));
        }
    }
}

extern "C" void kernel_launch(void* const* d_in, const int* in_sizes, int n_in,
                              void* d_out, int out_size, void* d_ws, size_t ws_size,
                              hipStream_t stream) {
    const float* x         = (const float*)d_in[0];
    const float* ln_gamma  = (const float*)d_in[1];
    const float* ln_beta   = (const float*)d_in[2];
    const float* in_proj_w = (const float*)d_in[3];
    const float* conv_w    = (const float*)d_in[4];
    const float* conv_b    = (const float*)d_in[5];
    const float* x_proj_w  = (const float*)d_in[6];
    const float* dt_proj_w = (const float*)d_in[7];
    const float* dt_proj_b = (const float*)d_in[8];
    const float* A_log     = (const float*)d_in[9];
    const float* D_param   = (const float*)d_in[10];
    const float* out_proj_w= (const float*)d_in[11];
    float* out = (float*)d_out;

    float* ws = (float*)d_ws;
    float* h     = ws;                               // 2,097,152 floats
    float* xz    = h     + (long)NTOK * D_MODEL;     // 8,388,608
    float* xb    = xz    + (long)NTOK * NPROJ;       // 4,194,304
    float* xpj   = xb    + (long)NTOK * D_INNER;     //   327,680
    float* delta = xpj   + (long)NTOK * XPJ_N;       // 4,194,304
    float* yfin  = delta + (long)NTOK * D_INNER;     // 4,194,304

    const long PH = (long)BATCH * NCHUNK * D_INNER * D_STATE;   // 1,048,576 floats
    // Aliased scratch with audited lifetimes:
    ushort* h_bf16  = (ushort*)h;              // dead after gemm2
    float*  hinit   = h + PH;                  // written phase B
    ushort* DTT     = (ushort*)h;              // dt_proj_w^T bf16 [2048][128]; after gemm2, until gemm5
    ushort* W2T     = (ushort*)xb;             // dead after gemm2 (conv overwrites)
    ushort* xb_bf16 = (ushort*)delta;          // conv→gemm4; gemm5 overwrites delta after
    ushort* XPT     = (ushort*)xpj;            // x_proj_w^T bf16 [160][2048]; dead after gemm4 (reduce overwrites)
    float*  Ppart   = yfin;                    // [8][2048][160] = 2,621,440 f; dead after reduce
    ushort* dtr     = (ushort*)(yfin + 3 * PH);// [2048][128] bf16; dead after gemm5
    float*  Pbuf    = yfin;                    // scan P
    float*  Hbuf    = yfin + PH;               // scan H
    ushort* y_bf16  = (ushort*)(yfin + 2 * PH);// scan_final out; overwrites dtr (dead)
    ushort* W7T     = (ushort*)xz;             // after scan_final

    // 0a. W2T = in_proj_w^T bf16 [4096][1024]
    transpose_bf16_kernel<<<dim3(NPROJ / 64, D_MODEL / 64), 256, 0, stream>>>(
        in_proj_w, W2T, D_MODEL, NPROJ);

    // 1. LayerNorm → bf16
    ln_kernel<<<NTOK, 256, 0, stream>>>(x, ln_gamma, ln_beta, h_bf16);

    // 2. xz = h @ in_proj_w (MFMA) [2048,1024]x[1024,4096]
    gemm_mfma_kernel<0><<<dim3(NPROJ / 128, NTOK / 128), 256, 0, stream>>>(
        h_bf16, W2T, nullptr, nullptr, xz, NTOK, NPROJ, D_MODEL);

    // 3. conv4 + bias + SiLU → xb f32 + bf16
    conv_silu_kernel<<<(NTOK * D_INNER) / 256, 256, 0, stream>>>(
        xz, conv_w, conv_b, xb, xb_bf16);

    // 3b. XPT = x_proj_w^T bf16 [160][2048] ; DTT = dt_proj_w^T bf16 [2048][128]
    transpose_bf16_kernel<<<dim3((XPJ_N + 63) / 64, D_INNER / 64), 256, 0, stream>>>(
        x_proj_w, XPT, D_INNER, XPJ_N);
    transpose_bf16_kernel<<<dim3(D_INNER / 64, DT_RANK / 64), 256, 0, stream>>>(
        dt_proj_w, DTT, DT_RANK, D_INNER);

    // 4. xpj partials (split-K MFMA) then reduce → xpj f32 + dtr bf16
    gemm4_mfma_kernel<<<dim3(SPLITK, NTOK / 64), 256, 0, stream>>>(
        xb_bf16, XPT, Ppart, NTOK, D_INNER);
    reduce_xpj_kernel<<<(NTOK * XPJ_N) / 256, 256, 0, stream>>>(Ppart, xpj, dtr);

    // 5. delta = softplus(dt_r @ dt_proj_w + b) (MFMA) [2048,128]x[128,2048]
    gemm_mfma_kernel<1><<<dim3(D_INNER / 128, NTOK / 128), 256, 0, stream>>>(
        dtr, DTT, dt_proj_b, nullptr, delta, NTOK, D_INNER, DT_RANK);

    // 6. chunked selective scan
    scan_partial_kernel<<<(BATCH * NCHUNK * D_INNER) / 16, 256, 0, stream>>>(
        delta, xb, xpj, A_log, Pbuf, Hbuf);
    scan_chunkscan_kernel<<<(BATCH * D_INNER * D_STATE) / 256, 256, 0, stream>>>(
        Pbuf, Hbuf, hinit);
    scan_final_kernel<<<(BATCH * NCHUNK * D_INNER) / 16, 256, 0, stream>>>(
        delta, xb, xpj, xz, A_log, D_param, hinit, y_bf16);

    // 6b. W7T = out_proj_w^T bf16 [1024][2048] (xz dead)
    transpose_bf16_kernel<<<dim3(D_MODEL / 64, D_INNER / 64), 256, 0, stream>>>(
        out_proj_w, W7T, D_INNER, D_MODEL);

    // 7. out = y @ out_proj_w + x (MFMA) [2048,2048]x[2048,1024]
    gemm_mfma_kernel<2><<<dim3(D_MODEL / 128, NTOK / 128), 256, 0, stream>>>(
        y_bf16, W7T, nullptr, x, out, NTOK, D_MODEL, D_INNER);
}

// Round 6
// 242.854 us; speedup vs baseline: 6.6374x; 1.2669x over previous
//
#include <hip/hip_runtime.h>
#include <hip/hip_bf16.h>

#define D_MODEL 1024
#define D_INNER 2048
#define NPROJ   4096   /* 2*D_INNER */
#define D_STATE 16
#define DT_RANK 128
#define XPJ_N   160    /* DT_RANK + 2*D_STATE */
#define SEQLEN  1024
#define BATCH   2
#define NTOK    2048   /* BATCH*SEQLEN */
#define CHUNK   64
#define NCHUNK  (SEQLEN / CHUNK)   /* 16 */
#define SPLITK  8

typedef short short8 __attribute__((ext_vector_type(8)));
typedef float f32x4 __attribute__((ext_vector_type(4)));

__device__ __forceinline__ float sigmoidf_(float x) { return 1.f / (1.f + __expf(-x)); }
__device__ __forceinline__ ushort f2bf_bits(float f) {
    __hip_bfloat16 h = __float2bfloat16(f);
    return *(ushort*)&h;
}

// ---------------- LayerNorm → bf16 output ----------------
__global__ __launch_bounds__(256) void ln_kernel(const float* __restrict__ x,
                                                 const float* __restrict__ g,
                                                 const float* __restrict__ be,
                                                 ushort* __restrict__ hb)
{
    int row = blockIdx.x;
    const float4* xr = (const float4*)(x + (long)row * D_MODEL);
    float4 v = xr[threadIdx.x];
    float s1 = v.x + v.y + v.z + v.w;
    float s2 = v.x*v.x + v.y*v.y + v.z*v.z + v.w*v.w;
    for (int off = 32; off >= 1; off >>= 1) {
        s1 += __shfl_down(s1, off);
        s2 += __shfl_down(s2, off);
    }
    __shared__ float red[8];
    int wid = threadIdx.x >> 6;
    if ((threadIdx.x & 63) == 0) { red[wid] = s1; red[4 + wid] = s2; }
    __syncthreads();
    float mu  = (red[0] + red[1] + red[2] + red[3]) * (1.f / D_MODEL);
    float ex2 = (red[4] + red[5] + red[6] + red[7]) * (1.f / D_MODEL);
    float inv = rsqrtf(ex2 - mu * mu + 1e-5f);
    float4 g4 = ((const float4*)g)[threadIdx.x];
    float4 b4 = ((const float4*)be)[threadIdx.x];
    ushort4 o;
    o.x = f2bf_bits((v.x - mu) * inv * g4.x + b4.x);
    o.y = f2bf_bits((v.y - mu) * inv * g4.y + b4.y);
    o.z = f2bf_bits((v.z - mu) * inv * g4.z + b4.z);
    o.w = f2bf_bits((v.w - mu) * inv * g4.w + b4.w);
    *(ushort4*)(hb + (long)row * D_MODEL + threadIdx.x * 4) = o;
}

// ---------------- f32 [R][C] → bf16 [C][R] transpose (guarded) ----------------
__global__ __launch_bounds__(256) void transpose_bf16_kernel(const float* __restrict__ in,
                                                             ushort* __restrict__ out,
                                                             int R, int C)
{
    __shared__ float tile[64][65];
    int c0 = blockIdx.x * 64, r0 = blockIdx.y * 64;
    #pragma unroll
    for (int i = 0; i < 16; ++i) {
        int idx = threadIdx.x + i * 256;
        int r = idx >> 6, c = idx & 63;
        tile[r][c] = (r0 + r < R && c0 + c < C) ? in[(long)(r0 + r) * C + (c0 + c)] : 0.f;
    }
    __syncthreads();
    #pragma unroll
    for (int i = 0; i < 16; ++i) {
        int idx = threadIdx.x + i * 256;
        int cc = idx >> 6, rr = idx & 63;
        if (c0 + cc < C && r0 + rr < R)
            out[(long)(c0 + cc) * R + (r0 + rr)] = f2bf_bits(tile[rr][cc]);
    }
}

// ---------------- bf16 MFMA GEMM: C[M,N] = A[M,K] * Bt[N,K]^T ----------------
template <int EPI>
__global__ __launch_bounds__(256) void gemm_mfma_kernel(const ushort* __restrict__ A,
                                                        const ushort* __restrict__ Bt,
                                                        const float* __restrict__ bias,
                                                        const float* __restrict__ resid,
                                                        float* __restrict__ C,
                                                        int M, int N, int K)
{
    __shared__ __align__(16) ushort Al[128 * 32];
    __shared__ __align__(16) ushort Bl[128 * 32];
    int tid = threadIdx.x;
    int lane = tid & 63;
    int w = tid >> 6, wr = w >> 1, wc = w & 1;
    int m0 = blockIdx.y * 128, n0 = blockIdx.x * 128;
    f32x4 acc[4][4];
    #pragma unroll
    for (int m = 0; m < 4; ++m)
        #pragma unroll
        for (int n = 0; n < 4; ++n) acc[m][n] = (f32x4){0.f, 0.f, 0.f, 0.f};
    int l15 = lane & 15, kq = lane >> 4;

    for (int k0 = 0; k0 < K; k0 += 32) {
        #pragma unroll
        for (int i = 0; i < 2; ++i) {
            int s = i * 256 + tid;
            int row = s >> 2, kg = s & 3;
            int kgl = kg ^ ((row >> 1) & 3);
            __builtin_amdgcn_global_load_lds(
                (const __attribute__((address_space(1))) void*)(A + (long)(m0 + row) * K + k0 + kgl * 8),
                (__attribute__((address_space(3))) void*)(Al + s * 8), 16, 0, 0);
            __builtin_amdgcn_global_load_lds(
                (const __attribute__((address_space(1))) void*)(Bt + (long)(n0 + row) * K + k0 + kgl * 8),
                (__attribute__((address_space(3))) void*)(Bl + s * 8), 16, 0, 0);
        }
        __syncthreads();
        short8 af[4], bf[4];
        #pragma unroll
        for (int m = 0; m < 4; ++m) {
            int row = wr * 64 + m * 16 + l15;
            af[m] = *(const short8*)&Al[row * 32 + (kq ^ ((row >> 1) & 3)) * 8];
        }
        #pragma unroll
        for (int n = 0; n < 4; ++n) {
            int row = wc * 64 + n * 16 + l15;
            bf[n] = *(const short8*)&Bl[row * 32 + (kq ^ ((row >> 1) & 3)) * 8];
        }
        #pragma unroll
        for (int m = 0; m < 4; ++m)
            #pragma unroll
            for (int n = 0; n < 4; ++n)
                acc[m][n] = __builtin_amdgcn_mfma_f32_16x16x32_bf16(af[m], bf[n], acc[m][n], 0, 0, 0);
        __syncthreads();
    }
    #pragma unroll
    for (int m = 0; m < 4; ++m) {
        #pragma unroll
        for (int n = 0; n < 4; ++n) {
            #pragma unroll
            for (int r = 0; r < 4; ++r) {
                int row = m0 + wr * 64 + m * 16 + kq * 4 + r;
                int col = n0 + wc * 64 + n * 16 + l15;
                float v = acc[m][n][r];
                if (EPI == 1) {
                    v += bias[col];
                    v = (v > 20.f) ? v : log1pf(__expf(v));
                } else if (EPI == 2) {
                    v += resid[(long)row * N + col];
                }
                C[(long)row * N + col] = v;
            }
        }
    }
}

// -------- split-K bf16 MFMA GEMM for xpj --------
__global__ __launch_bounds__(256) void gemm4_mfma_kernel(const ushort* __restrict__ A,
                                                         const ushort* __restrict__ Bt,
                                                         float* __restrict__ Ppart,
                                                         int M, int K)
{
    __shared__ __align__(16) ushort Al[64 * 32];
    __shared__ __align__(16) ushort Bl[160 * 32];
    int tid = threadIdx.x;
    int lane = tid & 63;
    int w = tid >> 6, wr = w >> 1, wc = w & 1;
    int sk = blockIdx.x;
    int m0 = blockIdx.y * 64;
    int kbase = sk * (K / SPLITK);
    f32x4 acc[2][5];
    #pragma unroll
    for (int m = 0; m < 2; ++m)
        #pragma unroll
        for (int n = 0; n < 5; ++n) acc[m][n] = (f32x4){0.f, 0.f, 0.f, 0.f};
    int l15 = lane & 15, kq = lane >> 4;

    for (int ks = 0; ks < K / SPLITK; ks += 32) {
        int k0 = kbase + ks;
        {
            int s = tid;
            int row = s >> 2, kg = s & 3;
            int kgl = kg ^ ((row >> 1) & 3);
            __builtin_amdgcn_global_load_lds(
                (const __attribute__((address_space(1))) void*)(A + (long)(m0 + row) * K + k0 + kgl * 8),
                (__attribute__((address_space(3))) void*)(Al + s * 8), 16, 0, 0);
        }
        #pragma unroll
        for (int i = 0; i < 3; ++i) {
            int s = i * 256 + tid;
            if (s < 640) {
                int row = s >> 2, kg = s & 3;
                int kgl = kg ^ ((row >> 1) & 3);
                __builtin_amdgcn_global_load_lds(
                    (const __attribute__((address_space(1))) void*)(Bt + (long)row * K + k0 + kgl * 8),
                    (__attribute__((address_space(3))) void*)(Bl + s * 8), 16, 0, 0);
            }
        }
        __syncthreads();
        short8 af[2], bf[5];
        #pragma unroll
        for (int m = 0; m < 2; ++m) {
            int row = wr * 32 + m * 16 + l15;
            af[m] = *(const short8*)&Al[row * 32 + (kq ^ ((row >> 1) & 3)) * 8];
        }
        #pragma unroll
        for (int n = 0; n < 5; ++n) {
            int row = wc * 80 + n * 16 + l15;
            bf[n] = *(const short8*)&Bl[row * 32 + (kq ^ ((row >> 1) & 3)) * 8];
        }
        #pragma unroll
        for (int m = 0; m < 2; ++m)
            #pragma unroll
            for (int n = 0; n < 5; ++n)
                acc[m][n] = __builtin_amdgcn_mfma_f32_16x16x32_bf16(af[m], bf[n], acc[m][n], 0, 0, 0);
        __syncthreads();
    }
    float* P = Ppart + (long)sk * M * XPJ_N;
    #pragma unroll
    for (int m = 0; m < 2; ++m) {
        #pragma unroll
        for (int n = 0; n < 5; ++n) {
            #pragma unroll
            for (int r = 0; r < 4; ++r) {
                int row = m0 + wr * 32 + m * 16 + kq * 4 + r;
                int col = wc * 80 + n * 16 + l15;
                P[(long)row * XPJ_N + col] = acc[m][n][r];
            }
        }
    }
}

// -------- reduce split-K partials → xpj f32 + dt_r bf16 --------
__global__ __launch_bounds__(256) void reduce_xpj_kernel(const float* __restrict__ Ppart,
                                                         float* __restrict__ xpj,
                                                         ushort* __restrict__ dtr)
{
    long i = (long)blockIdx.x * 256 + threadIdx.x;   // over NTOK*XPJ_N
    float s = 0.f;
    #pragma unroll
    for (int k = 0; k < SPLITK; ++k) s += Ppart[k * (long)NTOK * XPJ_N + i];
    xpj[i] = s;
    int col = (int)(i % XPJ_N);
    long row = i / XPJ_N;
    if (col < DT_RANK) dtr[row * DT_RANK + col] = f2bf_bits(s);
}

// ---------------- depthwise causal conv (width 4) + bias + SiLU; f32 + bf16 out -------
__global__ __launch_bounds__(256) void conv_silu_kernel(const float* __restrict__ xz,
                                                        const float* __restrict__ cw,
                                                        const float* __restrict__ cb,
                                                        float* __restrict__ xb,
                                                        ushort* __restrict__ xbb)
{
    long i = (long)blockIdx.x * 256 + threadIdx.x;  // over NTOK*D_INNER
    int d = (int)(i & (D_INNER - 1));
    long tok = i >> 11;
    int l = (int)(tok & (SEQLEN - 1));
    float w0 = cw[d * 4 + 0], w1 = cw[d * 4 + 1], w2 = cw[d * 4 + 2], w3 = cw[d * 4 + 3];
    float acc = cb[d];
    acc += xz[tok * NPROJ + d] * w3;
    if (l >= 1) acc += xz[(tok - 1) * NPROJ + d] * w2;
    if (l >= 2) acc += xz[(tok - 2) * NPROJ + d] * w1;
    if (l >= 3) acc += xz[(tok - 3) * NPROJ + d] * w0;
    float v = acc * sigmoidf_(acc);
    xb[i] = v;
    xbb[i] = f2bf_bits(v);
}

// ======================= chunked selective scan (4 lanes/channel) =======================
// Lane j of a channel owns states n = 4j..4j+3 in registers; B/C via float4 loads;
// y-dot is 4 in-register FMAs + 2 shuffles.

__global__ __launch_bounds__(256) void scan_partial_kernel(const float* __restrict__ delta,
                                                           const float* __restrict__ xb,
                                                           const float* __restrict__ xpj,
                                                           const float* __restrict__ A_log,
                                                           float* __restrict__ Pout,
                                                           float* __restrict__ Hout)
{
    int tid = threadIdx.x;
    int j = tid & 3, grp = tid >> 2;
    long gidx = (long)blockIdx.x * 64 + grp;      // over BATCH*NCHUNK*D_INNER
    int d = (int)(gidx & (D_INNER - 1));
    int c = (int)((gidx >> 11) & (NCHUNK - 1));
    int b = (int)(gidx >> 15);
    float4 al = *(const float4*)&A_log[d * D_STATE + 4 * j];
    float a0 = -__expf(al.x), a1 = -__expf(al.y), a2 = -__expf(al.z), a3 = -__expf(al.w);
    float h0 = 0.f, h1 = 0.f, h2 = 0.f, h3 = 0.f, cum = 0.f;
    long tok0 = (long)b * SEQLEN + c * CHUNK;
    const float* dp = delta + tok0 * D_INNER + d;
    const float* xp = xb + tok0 * D_INNER + d;
    const float* Bp = xpj + tok0 * XPJ_N + DT_RANK + 4 * j;
    for (int t = 0; t < CHUNK; ++t) {
        float dl = *dp;
        float x  = *xp;
        float4 Bv = *(const float4*)Bp;
        dp += D_INNER; xp += D_INNER; Bp += XPJ_N;
        cum += dl;
        float ux = dl * x;
        h0 = __expf(dl * a0) * h0 + ux * Bv.x;
        h1 = __expf(dl * a1) * h1 + ux * Bv.y;
        h2 = __expf(dl * a2) * h2 + ux * Bv.z;
        h3 = __expf(dl * a3) * h3 + ux * Bv.w;
    }
    long o = gidx * D_STATE + 4 * j;
    // P = prod(dA) = exp(a * sum(dl))
    *(float4*)&Pout[o] = (float4){__expf(a0 * cum), __expf(a1 * cum), __expf(a2 * cum), __expf(a3 * cum)};
    *(float4*)&Hout[o] = (float4){h0, h1, h2, h3};
}

__global__ __launch_bounds__(256) void scan_chunkscan_kernel(const float* __restrict__ P,
                                                             const float* __restrict__ H,
                                                             float* __restrict__ hinit)
{
    long i = (long)blockIdx.x * 256 + threadIdx.x;  // over BATCH*D_INNER*D_STATE
    int n = (int)(i & (D_STATE - 1));
    int d = (int)((i >> 4) & (D_INNER - 1));
    int b = (int)(i >> 15);
    float h = 0.f;
    for (int c = 0; c < NCHUNK; ++c) {
        long o = ((((long)b * NCHUNK + c) * D_INNER + d) * D_STATE) + n;
        hinit[o] = h;
        h = P[o] * h + H[o];
    }
}

__global__ __launch_bounds__(256) void scan_final_kernel(const float* __restrict__ delta,
                                                         const float* __restrict__ xb,
                                                         const float* __restrict__ xpj,
                                                         const float* __restrict__ xz,
                                                         const float* __restrict__ A_log,
                                                         const float* __restrict__ Dp,
                                                         const float* __restrict__ hinit,
                                                         ushort* __restrict__ yb)
{
    int tid = threadIdx.x;
    int j = tid & 3, grp = tid >> 2;
    long gidx = (long)blockIdx.x * 64 + grp;
    int d = (int)(gidx & (D_INNER - 1));
    int c = (int)((gidx >> 11) & (NCHUNK - 1));
    int b = (int)(gidx >> 15);
    float4 al = *(const float4*)&A_log[d * D_STATE + 4 * j];
    float a0 = -__expf(al.x), a1 = -__expf(al.y), a2 = -__expf(al.z), a3 = -__expf(al.w);
    float dpar = Dp[d];
    float4 hv = *(const float4*)&hinit[gidx * D_STATE + 4 * j];
    float h0 = hv.x, h1 = hv.y, h2 = hv.z, h3 = hv.w;
    long tok0 = (long)b * SEQLEN + c * CHUNK;
    const float* dp = delta + tok0 * D_INNER + d;
    const float* xp = xb + tok0 * D_INNER + d;
    const float* Bp = xpj + tok0 * XPJ_N + DT_RANK + 4 * j;
    const float* Cp = Bp + D_STATE;
    const float* zp = xz + tok0 * NPROJ + D_INNER + d;
    ushort* yp = yb + tok0 * D_INNER + d;
    for (int t = 0; t < CHUNK; ++t) {
        float dl = *dp;
        float x  = *xp;
        float4 Bv = *(const float4*)Bp;
        float4 Cv = *(const float4*)Cp;
        dp += D_INNER; xp += D_INNER; Bp += XPJ_N; Cp += XPJ_N;
        float ux = dl * x;
        h0 = __expf(dl * a0) * h0 + ux * Bv.x;
        h1 = __expf(dl * a1) * h1 + ux * Bv.y;
        h2 = __expf(dl * a2) * h2 + ux * Bv.z;
        h3 = __expf(dl * a3) * h3 + ux * Bv.w;
        float p = h0 * Cv.x + h1 * Cv.y + h2 * Cv.z + h3 * Cv.w;
        p += __shfl_xor(p, 1);
        p += __shfl_xor(p, 2);
        if (j == 0) {
            float z = *zp;
            float y = p + x * dpar;
            *yp = f2bf_bits(y * (z * sigmoidf_(z)));
        }
        zp += NPROJ; yp += D_INNER;
    }
}

extern "C" void kernel_launch(void* const* d_in, const int* in_sizes, int n_in,
                              void* d_out, int out_size, void* d_ws, size_t ws_size,
                              hipStream_t stream) {
    const float* x         = (const float*)d_in[0];
    const float* ln_gamma  = (const float*)d_in[1];
    const float* ln_beta   = (const float*)d_in[2];
    const float* in_proj_w = (const float*)d_in[3];
    const float* conv_w    = (const float*)d_in[4];
    const float* conv_b    = (const float*)d_in[5];
    const float* x_proj_w  = (const float*)d_in[6];
    const float* dt_proj_w = (const float*)d_in[7];
    const float* dt_proj_b = (const float*)d_in[8];
    const float* A_log     = (const float*)d_in[9];
    const float* D_param   = (const float*)d_in[10];
    const float* out_proj_w= (const float*)d_in[11];
    float* out = (float*)d_out;

    float* ws = (float*)d_ws;
    float* h     = ws;                               // 2,097,152 floats
    float* xz    = h     + (long)NTOK * D_MODEL;     // 8,388,608
    float* xb    = xz    + (long)NTOK * NPROJ;       // 4,194,304
    float* xpj   = xb    + (long)NTOK * D_INNER;     //   327,680
    float* delta = xpj   + (long)NTOK * XPJ_N;       // 4,194,304
    float* yfin  = delta + (long)NTOK * D_INNER;     // 4,194,304

    const long PH = (long)BATCH * NCHUNK * D_INNER * D_STATE;   // 1,048,576 floats
    ushort* h_bf16  = (ushort*)h;              // dead after gemm2
    float*  hinit   = h + PH;                  // written phase B
    ushort* DTT     = (ushort*)h;              // dt_proj_w^T bf16; after gemm2, until gemm5
    ushort* W2T     = (ushort*)xb;             // dead after gemm2 (conv overwrites)
    ushort* xb_bf16 = (ushort*)delta;          // conv→gemm4; gemm5 overwrites delta after
    ushort* XPT     = (ushort*)xpj;            // x_proj_w^T bf16; dead after gemm4
    float*  Ppart   = yfin;                    // [8][2048][160]; dead after reduce
    ushort* dtr     = (ushort*)(yfin + 3 * PH);// [2048][128] bf16; dead after gemm5
    float*  Pbuf    = yfin;                    // scan P
    float*  Hbuf    = yfin + PH;               // scan H
    ushort* y_bf16  = (ushort*)(yfin + 2 * PH);// scan_final out
    ushort* W7T     = (ushort*)xz;             // after scan_final

    // 0a. W2T = in_proj_w^T bf16 [4096][1024]
    transpose_bf16_kernel<<<dim3(NPROJ / 64, D_MODEL / 64), 256, 0, stream>>>(
        in_proj_w, W2T, D_MODEL, NPROJ);

    // 1. LayerNorm → bf16
    ln_kernel<<<NTOK, 256, 0, stream>>>(x, ln_gamma, ln_beta, h_bf16);

    // 2. xz = h @ in_proj_w (MFMA) [2048,1024]x[1024,4096]
    gemm_mfma_kernel<0><<<dim3(NPROJ / 128, NTOK / 128), 256, 0, stream>>>(
        h_bf16, W2T, nullptr, nullptr, xz, NTOK, NPROJ, D_MODEL);

    // 3. conv4 + bias + SiLU → xb f32 + bf16
    conv_silu_kernel<<<(NTOK * D_INNER) / 256, 256, 0, stream>>>(
        xz, conv_w, conv_b, xb, xb_bf16);

    // 3b. XPT = x_proj_w^T ; DTT = dt_proj_w^T
    transpose_bf16_kernel<<<dim3((XPJ_N + 63) / 64, D_INNER / 64), 256, 0, stream>>>(
        x_proj_w, XPT, D_INNER, XPJ_N);
    transpose_bf16_kernel<<<dim3(D_INNER / 64, DT_RANK / 64), 256, 0, stream>>>(
        dt_proj_w, DTT, DT_RANK, D_INNER);

    // 4. xpj partials (split-K MFMA) then reduce
    gemm4_mfma_kernel<<<dim3(SPLITK, NTOK / 64), 256, 0, stream>>>(
        xb_bf16, XPT, Ppart, NTOK, D_INNER);
    reduce_xpj_kernel<<<(NTOK * XPJ_N) / 256, 256, 0, stream>>>(Ppart, xpj, dtr);

    // 5. delta = softplus(dt_r @ dt_proj_w + b) (MFMA)
    gemm_mfma_kernel<1><<<dim3(D_INNER / 128, NTOK / 128), 256, 0, stream>>>(
        dtr, DTT, dt_proj_b, nullptr, delta, NTOK, D_INNER, DT_RANK);

    // 6. chunked selective scan (4 lanes/channel)
    scan_partial_kernel<<<(BATCH * NCHUNK * D_INNER) / 64, 256, 0, stream>>>(
        delta, xb, xpj, A_log, Pbuf, Hbuf);
    scan_chunkscan_kernel<<<(BATCH * D_INNER * D_STATE) / 256, 256, 0, stream>>>(
        Pbuf, Hbuf, hinit);
    scan_final_kernel<<<(BATCH * NCHUNK * D_INNER) / 64, 256, 0, stream>>>(
        delta, xb, xpj, xz, A_log, D_param, hinit, y_bf16);

    // 6b. W7T = out_proj_w^T bf16 (xz dead)
    transpose_bf16_kernel<<<dim3(D_MODEL / 64, D_INNER / 64), 256, 0, stream>>>(
        out_proj_w, W7T, D_INNER, D_MODEL);

    // 7. out = y @ out_proj_w + x (MFMA)
    gemm_mfma_kernel<2><<<dim3(D_MODEL / 128, NTOK / 128), 256, 0, stream>>>(
        y_bf16, W7T, nullptr, x, out, NTOK, D_MODEL, D_INNER);
}

// Round 7
// 219.361 us; speedup vs baseline: 7.3482x; 1.1071x over previous
//
#include <hip/hip_runtime.h>
#include <hip/hip_bf16.h>

#define D_MODEL 1024
#define D_INNER 2048
#define NPROJ   4096   /* 2*D_INNER */
#define D_STATE 16
#define DT_RANK 128
#define XPJ_N   160    /* DT_RANK + 2*D_STATE */
#define SEQLEN  1024
#define BATCH   2
#define NTOK    2048   /* BATCH*SEQLEN */
#define CHUNK   32
#define NCHUNK  (SEQLEN / CHUNK)   /* 32 */
#define LOG2_NCHUNK 5
#define SPLITK  8

typedef short short8 __attribute__((ext_vector_type(8)));
typedef float f32x4 __attribute__((ext_vector_type(4)));

__device__ __forceinline__ float sigmoidf_(float x) { return 1.f / (1.f + __expf(-x)); }
__device__ __forceinline__ ushort f2bf_bits(float f) {
    __hip_bfloat16 h = __float2bfloat16(f);
    return *(ushort*)&h;
}

// ---------------- LayerNorm → bf16 output ----------------
__global__ __launch_bounds__(256) void ln_kernel(const float* __restrict__ x,
                                                 const float* __restrict__ g,
                                                 const float* __restrict__ be,
                                                 ushort* __restrict__ hb)
{
    int row = blockIdx.x;
    const float4* xr = (const float4*)(x + (long)row * D_MODEL);
    float4 v = xr[threadIdx.x];
    float s1 = v.x + v.y + v.z + v.w;
    float s2 = v.x*v.x + v.y*v.y + v.z*v.z + v.w*v.w;
    for (int off = 32; off >= 1; off >>= 1) {
        s1 += __shfl_down(s1, off);
        s2 += __shfl_down(s2, off);
    }
    __shared__ float red[8];
    int wid = threadIdx.x >> 6;
    if ((threadIdx.x & 63) == 0) { red[wid] = s1; red[4 + wid] = s2; }
    __syncthreads();
    float mu  = (red[0] + red[1] + red[2] + red[3]) * (1.f / D_MODEL);
    float ex2 = (red[4] + red[5] + red[6] + red[7]) * (1.f / D_MODEL);
    float inv = rsqrtf(ex2 - mu * mu + 1e-5f);
    float4 g4 = ((const float4*)g)[threadIdx.x];
    float4 b4 = ((const float4*)be)[threadIdx.x];
    ushort4 o;
    o.x = f2bf_bits((v.x - mu) * inv * g4.x + b4.x);
    o.y = f2bf_bits((v.y - mu) * inv * g4.y + b4.y);
    o.z = f2bf_bits((v.z - mu) * inv * g4.z + b4.z);
    o.w = f2bf_bits((v.w - mu) * inv * g4.w + b4.w);
    *(ushort4*)(hb + (long)row * D_MODEL + threadIdx.x * 4) = o;
}

// ---------------- f32 [R][C] → bf16 [C][R] transpose (guarded) ----------------
__global__ __launch_bounds__(256) void transpose_bf16_kernel(const float* __restrict__ in,
                                                             ushort* __restrict__ out,
                                                             int R, int C)
{
    __shared__ float tile[64][65];
    int c0 = blockIdx.x * 64, r0 = blockIdx.y * 64;
    #pragma unroll
    for (int i = 0; i < 16; ++i) {
        int idx = threadIdx.x + i * 256;
        int r = idx >> 6, c = idx & 63;
        tile[r][c] = (r0 + r < R && c0 + c < C) ? in[(long)(r0 + r) * C + (c0 + c)] : 0.f;
    }
    __syncthreads();
    #pragma unroll
    for (int i = 0; i < 16; ++i) {
        int idx = threadIdx.x + i * 256;
        int cc = idx >> 6, rr = idx & 63;
        if (c0 + cc < C && r0 + rr < R)
            out[(long)(c0 + cc) * R + (r0 + rr)] = f2bf_bits(tile[rr][cc]);
    }
}

// ---------------- bf16 MFMA GEMM 128x128: C[M,N] = A[M,K] * Bt[N,K]^T ----------------
template <int EPI>
__global__ __launch_bounds__(256) void gemm_mfma_kernel(const ushort* __restrict__ A,
                                                        const ushort* __restrict__ Bt,
                                                        const float* __restrict__ bias,
                                                        const float* __restrict__ resid,
                                                        float* __restrict__ C,
                                                        int M, int N, int K)
{
    __shared__ __align__(16) ushort Al[128 * 32];
    __shared__ __align__(16) ushort Bl[128 * 32];
    int tid = threadIdx.x;
    int lane = tid & 63;
    int w = tid >> 6, wr = w >> 1, wc = w & 1;
    int m0 = blockIdx.y * 128, n0 = blockIdx.x * 128;
    f32x4 acc[4][4];
    #pragma unroll
    for (int m = 0; m < 4; ++m)
        #pragma unroll
        for (int n = 0; n < 4; ++n) acc[m][n] = (f32x4){0.f, 0.f, 0.f, 0.f};
    int l15 = lane & 15, kq = lane >> 4;

    for (int k0 = 0; k0 < K; k0 += 32) {
        #pragma unroll
        for (int i = 0; i < 2; ++i) {
            int s = i * 256 + tid;
            int row = s >> 2, kg = s & 3;
            int kgl = kg ^ ((row >> 1) & 3);
            __builtin_amdgcn_global_load_lds(
                (const __attribute__((address_space(1))) void*)(A + (long)(m0 + row) * K + k0 + kgl * 8),
                (__attribute__((address_space(3))) void*)(Al + s * 8), 16, 0, 0);
            __builtin_amdgcn_global_load_lds(
                (const __attribute__((address_space(1))) void*)(Bt + (long)(n0 + row) * K + k0 + kgl * 8),
                (__attribute__((address_space(3))) void*)(Bl + s * 8), 16, 0, 0);
        }
        __syncthreads();
        short8 af[4], bf[4];
        #pragma unroll
        for (int m = 0; m < 4; ++m) {
            int row = wr * 64 + m * 16 + l15;
            af[m] = *(const short8*)&Al[row * 32 + (kq ^ ((row >> 1) & 3)) * 8];
        }
        #pragma unroll
        for (int n = 0; n < 4; ++n) {
            int row = wc * 64 + n * 16 + l15;
            bf[n] = *(const short8*)&Bl[row * 32 + (kq ^ ((row >> 1) & 3)) * 8];
        }
        #pragma unroll
        for (int m = 0; m < 4; ++m)
            #pragma unroll
            for (int n = 0; n < 4; ++n)
                acc[m][n] = __builtin_amdgcn_mfma_f32_16x16x32_bf16(af[m], bf[n], acc[m][n], 0, 0, 0);
        __syncthreads();
    }
    #pragma unroll
    for (int m = 0; m < 4; ++m) {
        #pragma unroll
        for (int n = 0; n < 4; ++n) {
            #pragma unroll
            for (int r = 0; r < 4; ++r) {
                int row = m0 + wr * 64 + m * 16 + kq * 4 + r;
                int col = n0 + wc * 64 + n * 16 + l15;
                float v = acc[m][n][r];
                if (EPI == 1) {
                    v += bias[col];
                    v = (v > 20.f) ? v : log1pf(__expf(v));
                } else if (EPI == 2) {
                    v += resid[(long)row * N + col];
                }
                C[(long)row * N + col] = v;
            }
        }
    }
}

// ---------------- bf16 MFMA GEMM 128x64 (for out_proj: doubles grid) ----------------
template <int EPI>
__global__ __launch_bounds__(256) void gemm_mfma64_kernel(const ushort* __restrict__ A,
                                                          const ushort* __restrict__ Bt,
                                                          const float* __restrict__ resid,
                                                          float* __restrict__ C,
                                                          int M, int N, int K)
{
    __shared__ __align__(16) ushort Al[128 * 32];
    __shared__ __align__(16) ushort Bl[64 * 32];
    int tid = threadIdx.x;
    int lane = tid & 63;
    int w = tid >> 6, wr = w >> 1, wc = w & 1;   // 2x2 waves over (64 rows x 32 cols)
    int m0 = blockIdx.y * 128, n0 = blockIdx.x * 64;
    f32x4 acc[4][2];
    #pragma unroll
    for (int m = 0; m < 4; ++m)
        #pragma unroll
        for (int n = 0; n < 2; ++n) acc[m][n] = (f32x4){0.f, 0.f, 0.f, 0.f};
    int l15 = lane & 15, kq = lane >> 4;

    for (int k0 = 0; k0 < K; k0 += 32) {
        #pragma unroll
        for (int i = 0; i < 2; ++i) {   // A: 128 rows x 4 slots
            int s = i * 256 + tid;
            int row = s >> 2, kg = s & 3;
            int kgl = kg ^ ((row >> 1) & 3);
            __builtin_amdgcn_global_load_lds(
                (const __attribute__((address_space(1))) void*)(A + (long)(m0 + row) * K + k0 + kgl * 8),
                (__attribute__((address_space(3))) void*)(Al + s * 8), 16, 0, 0);
        }
        {   // B: 64 rows x 4 slots = 256
            int s = tid;
            int row = s >> 2, kg = s & 3;
            int kgl = kg ^ ((row >> 1) & 3);
            __builtin_amdgcn_global_load_lds(
                (const __attribute__((address_space(1))) void*)(Bt + (long)(n0 + row) * K + k0 + kgl * 8),
                (__attribute__((address_space(3))) void*)(Bl + s * 8), 16, 0, 0);
        }
        __syncthreads();
        short8 af[4], bf[2];
        #pragma unroll
        for (int m = 0; m < 4; ++m) {
            int row = wr * 64 + m * 16 + l15;
            af[m] = *(const short8*)&Al[row * 32 + (kq ^ ((row >> 1) & 3)) * 8];
        }
        #pragma unroll
        for (int n = 0; n < 2; ++n) {
            int row = wc * 32 + n * 16 + l15;
            bf[n] = *(const short8*)&Bl[row * 32 + (kq ^ ((row >> 1) & 3)) * 8];
        }
        #pragma unroll
        for (int m = 0; m < 4; ++m)
            #pragma unroll
            for (int n = 0; n < 2; ++n)
                acc[m][n] = __builtin_amdgcn_mfma_f32_16x16x32_bf16(af[m], bf[n], acc[m][n], 0, 0, 0);
        __syncthreads();
    }
    #pragma unroll
    for (int m = 0; m < 4; ++m) {
        #pragma unroll
        for (int n = 0; n < 2; ++n) {
            #pragma unroll
            for (int r = 0; r < 4; ++r) {
                int row = m0 + wr * 64 + m * 16 + kq * 4 + r;
                int col = n0 + wc * 32 + n * 16 + l15;
                float v = acc[m][n][r];
                if (EPI == 2) v += resid[(long)row * N + col];
                C[(long)row * N + col] = v;
            }
        }
    }
}

// -------- split-K bf16 MFMA GEMM for xpj --------
__global__ __launch_bounds__(256) void gemm4_mfma_kernel(const ushort* __restrict__ A,
                                                         const ushort* __restrict__ Bt,
                                                         float* __restrict__ Ppart,
                                                         int M, int K)
{
    __shared__ __align__(16) ushort Al[64 * 32];
    __shared__ __align__(16) ushort Bl[160 * 32];
    int tid = threadIdx.x;
    int lane = tid & 63;
    int w = tid >> 6, wr = w >> 1, wc = w & 1;
    int sk = blockIdx.x;
    int m0 = blockIdx.y * 64;
    int kbase = sk * (K / SPLITK);
    f32x4 acc[2][5];
    #pragma unroll
    for (int m = 0; m < 2; ++m)
        #pragma unroll
        for (int n = 0; n < 5; ++n) acc[m][n] = (f32x4){0.f, 0.f, 0.f, 0.f};
    int l15 = lane & 15, kq = lane >> 4;

    for (int ks = 0; ks < K / SPLITK; ks += 32) {
        int k0 = kbase + ks;
        {
            int s = tid;
            int row = s >> 2, kg = s & 3;
            int kgl = kg ^ ((row >> 1) & 3);
            __builtin_amdgcn_global_load_lds(
                (const __attribute__((address_space(1))) void*)(A + (long)(m0 + row) * K + k0 + kgl * 8),
                (__attribute__((address_space(3))) void*)(Al + s * 8), 16, 0, 0);
        }
        #pragma unroll
        for (int i = 0; i < 3; ++i) {
            int s = i * 256 + tid;
            if (s < 640) {
                int row = s >> 2, kg = s & 3;
                int kgl = kg ^ ((row >> 1) & 3);
                __builtin_amdgcn_global_load_lds(
                    (const __attribute__((address_space(1))) void*)(Bt + (long)row * K + k0 + kgl * 8),
                    (__attribute__((address_space(3))) void*)(Bl + s * 8), 16, 0, 0);
            }
        }
        __syncthreads();
        short8 af[2], bf[5];
        #pragma unroll
        for (int m = 0; m < 2; ++m) {
            int row = wr * 32 + m * 16 + l15;
            af[m] = *(const short8*)&Al[row * 32 + (kq ^ ((row >> 1) & 3)) * 8];
        }
        #pragma unroll
        for (int n = 0; n < 5; ++n) {
            int row = wc * 80 + n * 16 + l15;
            bf[n] = *(const short8*)&Bl[row * 32 + (kq ^ ((row >> 1) & 3)) * 8];
        }
        #pragma unroll
        for (int m = 0; m < 2; ++m)
            #pragma unroll
            for (int n = 0; n < 5; ++n)
                acc[m][n] = __builtin_amdgcn_mfma_f32_16x16x32_bf16(af[m], bf[n], acc[m][n], 0, 0, 0);
        __syncthreads();
    }
    float* P = Ppart + (long)sk * M * XPJ_N;
    #pragma unroll
    for (int m = 0; m < 2; ++m) {
        #pragma unroll
        for (int n = 0; n < 5; ++n) {
            #pragma unroll
            for (int r = 0; r < 4; ++r) {
                int row = m0 + wr * 32 + m * 16 + kq * 4 + r;
                int col = wc * 80 + n * 16 + l15;
                P[(long)row * XPJ_N + col] = acc[m][n][r];
            }
        }
    }
}

// -------- reduce split-K partials → xpj f32 + dt_r bf16 --------
__global__ __launch_bounds__(256) void reduce_xpj_kernel(const float* __restrict__ Ppart,
                                                         float* __restrict__ xpj,
                                                         ushort* __restrict__ dtr)
{
    long i = (long)blockIdx.x * 256 + threadIdx.x;   // over NTOK*XPJ_N
    float s = 0.f;
    #pragma unroll
    for (int k = 0; k < SPLITK; ++k) s += Ppart[k * (long)NTOK * XPJ_N + i];
    xpj[i] = s;
    int col = (int)(i % XPJ_N);
    long row = i / XPJ_N;
    if (col < DT_RANK) dtr[row * DT_RANK + col] = f2bf_bits(s);
}

// ---------------- depthwise causal conv (width 4) + bias + SiLU; f32 + bf16 out -------
__global__ __launch_bounds__(256) void conv_silu_kernel(const float* __restrict__ xz,
                                                        const float* __restrict__ cw,
                                                        const float* __restrict__ cb,
                                                        float* __restrict__ xb,
                                                        ushort* __restrict__ xbb)
{
    long i = (long)blockIdx.x * 256 + threadIdx.x;  // over NTOK*D_INNER
    int d = (int)(i & (D_INNER - 1));
    long tok = i >> 11;
    int l = (int)(tok & (SEQLEN - 1));
    float w0 = cw[d * 4 + 0], w1 = cw[d * 4 + 1], w2 = cw[d * 4 + 2], w3 = cw[d * 4 + 3];
    float acc = cb[d];
    acc += xz[tok * NPROJ + d] * w3;
    if (l >= 1) acc += xz[(tok - 1) * NPROJ + d] * w2;
    if (l >= 2) acc += xz[(tok - 2) * NPROJ + d] * w1;
    if (l >= 3) acc += xz[(tok - 3) * NPROJ + d] * w0;
    float v = acc * sigmoidf_(acc);
    xb[i] = v;
    xbb[i] = f2bf_bits(v);
}

// ======================= chunked selective scan (4 lanes/channel, CHUNK=32) ==========
__global__ __launch_bounds__(256) void scan_partial_kernel(const float* __restrict__ delta,
                                                           const float* __restrict__ xb,
                                                           const float* __restrict__ xpj,
                                                           const float* __restrict__ A_log,
                                                           float* __restrict__ Pout,
                                                           float* __restrict__ Hout)
{
    int tid = threadIdx.x;
    int j = tid & 3, grp = tid >> 2;
    long gidx = (long)blockIdx.x * 64 + grp;      // over BATCH*NCHUNK*D_INNER
    int d = (int)(gidx & (D_INNER - 1));
    int c = (int)((gidx >> 11) & (NCHUNK - 1));
    int b = (int)(gidx >> (11 + LOG2_NCHUNK));
    float4 al = *(const float4*)&A_log[d * D_STATE + 4 * j];
    float a0 = -__expf(al.x), a1 = -__expf(al.y), a2 = -__expf(al.z), a3 = -__expf(al.w);
    float h0 = 0.f, h1 = 0.f, h2 = 0.f, h3 = 0.f, cum = 0.f;
    long tok0 = (long)b * SEQLEN + c * CHUNK;
    const float* dp = delta + tok0 * D_INNER + d;
    const float* xp = xb + tok0 * D_INNER + d;
    const float* Bp = xpj + tok0 * XPJ_N + DT_RANK + 4 * j;
    for (int t = 0; t < CHUNK; ++t) {
        float dl = *dp;
        float x  = *xp;
        float4 Bv = *(const float4*)Bp;
        dp += D_INNER; xp += D_INNER; Bp += XPJ_N;
        cum += dl;
        float ux = dl * x;
        h0 = __expf(dl * a0) * h0 + ux * Bv.x;
        h1 = __expf(dl * a1) * h1 + ux * Bv.y;
        h2 = __expf(dl * a2) * h2 + ux * Bv.z;
        h3 = __expf(dl * a3) * h3 + ux * Bv.w;
    }
    long o = gidx * D_STATE + 4 * j;
    *(float4*)&Pout[o] = (float4){__expf(a0 * cum), __expf(a1 * cum), __expf(a2 * cum), __expf(a3 * cum)};
    *(float4*)&Hout[o] = (float4){h0, h1, h2, h3};
}

__global__ __launch_bounds__(256) void scan_chunkscan_kernel(const float* __restrict__ P,
                                                             const float* __restrict__ H,
                                                             float* __restrict__ hinit)
{
    long i = (long)blockIdx.x * 256 + threadIdx.x;  // over BATCH*D_INNER*D_STATE
    int n = (int)(i & (D_STATE - 1));
    int d = (int)((i >> 4) & (D_INNER - 1));
    int b = (int)(i >> 15);
    float h = 0.f;
    for (int c = 0; c < NCHUNK; ++c) {
        long o = ((((long)b * NCHUNK + c) * D_INNER + d) * D_STATE) + n;
        hinit[o] = h;
        h = P[o] * h + H[o];
    }
}

__global__ __launch_bounds__(256) void scan_final_kernel(const float* __restrict__ delta,
                                                         const float* __restrict__ xb,
                                                         const float* __restrict__ xpj,
                                                         const float* __restrict__ xz,
                                                         const float* __restrict__ A_log,
                                                         const float* __restrict__ Dp,
                                                         const float* __restrict__ hinit,
                                                         ushort* __restrict__ yb)
{
    int tid = threadIdx.x;
    int j = tid & 3, grp = tid >> 2;
    long gidx = (long)blockIdx.x * 64 + grp;
    int d = (int)(gidx & (D_INNER - 1));
    int c = (int)((gidx >> 11) & (NCHUNK - 1));
    int b = (int)(gidx >> (11 + LOG2_NCHUNK));
    float4 al = *(const float4*)&A_log[d * D_STATE + 4 * j];
    float a0 = -__expf(al.x), a1 = -__expf(al.y), a2 = -__expf(al.z), a3 = -__expf(al.w);
    float dpar = Dp[d];
    float4 hv = *(const float4*)&hinit[gidx * D_STATE + 4 * j];
    float h0 = hv.x, h1 = hv.y, h2 = hv.z, h3 = hv.w;
    long tok0 = (long)b * SEQLEN + c * CHUNK;
    const float* dp = delta + tok0 * D_INNER + d;
    const float* xp = xb + tok0 * D_INNER + d;
    const float* Bp = xpj + tok0 * XPJ_N + DT_RANK + 4 * j;
    const float* Cp = Bp + D_STATE;
    const float* zp = xz + tok0 * NPROJ + D_INNER + d;
    ushort* yp = yb + tok0 * D_INNER + d;
    for (int t = 0; t < CHUNK; ++t) {
        float dl = *dp;
        float x  = *xp;
        float4 Bv = *(const float4*)Bp;
        float4 Cv = *(const float4*)Cp;
        dp += D_INNER; xp += D_INNER; Bp += XPJ_N; Cp += XPJ_N;
        float ux = dl * x;
        h0 = __expf(dl * a0) * h0 + ux * Bv.x;
        h1 = __expf(dl * a1) * h1 + ux * Bv.y;
        h2 = __expf(dl * a2) * h2 + ux * Bv.z;
        h3 = __expf(dl * a3) * h3 + ux * Bv.w;
        float p = h0 * Cv.x + h1 * Cv.y + h2 * Cv.z + h3 * Cv.w;
        p += __shfl_xor(p, 1);
        p += __shfl_xor(p, 2);
        if (j == 0) {
            float z = *zp;
            float y = p + x * dpar;
            *yp = f2bf_bits(y * (z * sigmoidf_(z)));
        }
        zp += NPROJ; yp += D_INNER;
    }
}

extern "C" void kernel_launch(void* const* d_in, const int* in_sizes, int n_in,
                              void* d_out, int out_size, void* d_ws, size_t ws_size,
                              hipStream_t stream) {
    const float* x         = (const float*)d_in[0];
    const float* ln_gamma  = (const float*)d_in[1];
    const float* ln_beta   = (const float*)d_in[2];
    const float* in_proj_w = (const float*)d_in[3];
    const float* conv_w    = (const float*)d_in[4];
    const float* conv_b    = (const float*)d_in[5];
    const float* x_proj_w  = (const float*)d_in[6];
    const float* dt_proj_w = (const float*)d_in[7];
    const float* dt_proj_b = (const float*)d_in[8];
    const float* A_log     = (const float*)d_in[9];
    const float* D_param   = (const float*)d_in[10];
    const float* out_proj_w= (const float*)d_in[11];
    float* out = (float*)d_out;

    float* ws = (float*)d_ws;
    float* h     = ws;                               // 2,097,152 floats
    float* xz    = h     + (long)NTOK * D_MODEL;     // 8,388,608
    float* xb    = xz    + (long)NTOK * NPROJ;       // 4,194,304
    float* xpj   = xb    + (long)NTOK * D_INNER;     //   327,680
    float* delta = xpj   + (long)NTOK * XPJ_N;       // 4,194,304
    float* yfin  = delta + (long)NTOK * D_INNER;     // 4,194,304

    const long PH = (long)BATCH * NCHUNK * D_INNER * D_STATE;   // 2,097,152 floats
    // Aliased scratch, lifetimes stream-ordered:
    ushort* h_bf16  = (ushort*)h;              // dead after gemm2
    ushort* DTT     = (ushort*)h;              // dt_proj_w^T bf16; 3b → gemm5
    float*  hinit   = h;                       // chunkscan → scan_final (exactly fills h slot)
    ushort* W2T     = (ushort*)xb;             // dead after gemm2 (conv overwrites)
    ushort* xb_bf16 = (ushort*)delta;          // conv → gemm4 (gemm5 then overwrites delta)
    ushort* XPT     = (ushort*)xpj;            // x_proj_w^T bf16; dead after gemm4
    float*  Ppart   = yfin;                    // [8][2048][160] = 2,621,440 f; dead after reduce
    ushort* dtr     = (ushort*)(yfin + (long)SPLITK * NTOK * XPJ_N); // 131,072 f; reduce → gemm5
    float*  Pbuf    = yfin;                    // scan P   [PH]
    float*  Hbuf    = yfin + PH;               // scan H   [PH]  (fills yfin slot exactly)
    ushort* y_bf16  = (ushort*)yfin;           // scan_final out (Pbuf dead after chunkscan)
    ushort* W7T     = (ushort*)xz;             // after scan_final (xz dead)

    // 0a. W2T = in_proj_w^T bf16 [4096][1024]
    transpose_bf16_kernel<<<dim3(NPROJ / 64, D_MODEL / 64), 256, 0, stream>>>(
        in_proj_w, W2T, D_MODEL, NPROJ);

    // 1. LayerNorm → bf16
    ln_kernel<<<NTOK, 256, 0, stream>>>(x, ln_gamma, ln_beta, h_bf16);

    // 2. xz = h @ in_proj_w (MFMA) [2048,1024]x[1024,4096]
    gemm_mfma_kernel<0><<<dim3(NPROJ / 128, NTOK / 128), 256, 0, stream>>>(
        h_bf16, W2T, nullptr, nullptr, xz, NTOK, NPROJ, D_MODEL);

    // 3. conv4 + bias + SiLU → xb f32 + bf16
    conv_silu_kernel<<<(NTOK * D_INNER) / 256, 256, 0, stream>>>(
        xz, conv_w, conv_b, xb, xb_bf16);

    // 3b. XPT = x_proj_w^T ; DTT = dt_proj_w^T
    transpose_bf16_kernel<<<dim3((XPJ_N + 63) / 64, D_INNER / 64), 256, 0, stream>>>(
        x_proj_w, XPT, D_INNER, XPJ_N);
    transpose_bf16_kernel<<<dim3(D_INNER / 64, DT_RANK / 64), 256, 0, stream>>>(
        dt_proj_w, DTT, DT_RANK, D_INNER);

    // 4. xpj partials (split-K MFMA) then reduce
    gemm4_mfma_kernel<<<dim3(SPLITK, NTOK / 64), 256, 0, stream>>>(
        xb_bf16, XPT, Ppart, NTOK, D_INNER);
    reduce_xpj_kernel<<<(NTOK * XPJ_N) / 256, 256, 0, stream>>>(Ppart, xpj, dtr);

    // 5. delta = softplus(dt_r @ dt_proj_w + b) (MFMA)
    gemm_mfma_kernel<1><<<dim3(D_INNER / 128, NTOK / 128), 256, 0, stream>>>(
        dtr, DTT, dt_proj_b, nullptr, delta, NTOK, D_INNER, DT_RANK);

    // 6. chunked selective scan (4 lanes/channel, CHUNK=32)
    scan_partial_kernel<<<(BATCH * NCHUNK * D_INNER) / 64, 256, 0, stream>>>(
        delta, xb, xpj, A_log, Pbuf, Hbuf);
    scan_chunkscan_kernel<<<(BATCH * D_INNER * D_STATE) / 256, 256, 0, stream>>>(
        Pbuf, Hbuf, hinit);
    scan_final_kernel<<<(BATCH * NCHUNK * D_INNER) / 64, 256, 0, stream>>>(
        delta, xb, xpj, xz, A_log, D_param, hinit, y_bf16);

    // 6b. W7T = out_proj_w^T bf16 (xz dead)
    transpose_bf16_kernel<<<dim3(D_MODEL / 64, D_INNER / 64), 256, 0, stream>>>(
        out_proj_w, W7T, D_INNER, D_MODEL);

    // 7. out = y @ out_proj_w + x (MFMA, 128x64 tile → 256 blocks)
    gemm_mfma64_kernel<2><<<dim3(D_MODEL / 64, NTOK / 128), 256, 0, stream>>>(
        y_bf16, W7T, x, out, NTOK, D_MODEL, D_INNER);
}

// Round 8
// 208.779 us; speedup vs baseline: 7.7206x; 1.0507x over previous
//
#include <hip/hip_runtime.h>
#include <hip/hip_bf16.h>

#define D_MODEL 1024
#define D_INNER 2048
#define NPROJ   4096   /* 2*D_INNER */
#define D_STATE 16
#define DT_RANK 128
#define XPJ_N   160    /* DT_RANK + 2*D_STATE */
#define SEQLEN  1024
#define BATCH   2
#define NTOK    2048   /* BATCH*SEQLEN */
#define CHUNK   32
#define NCHUNK  (SEQLEN / CHUNK)   /* 32 */
#define LOG2_NCHUNK 5
#define SPLITK  8      /* gemm4 split */
#define OP_SPLITK 4    /* out_proj split */

typedef short short8 __attribute__((ext_vector_type(8)));
typedef float f32x4 __attribute__((ext_vector_type(4)));

__device__ __forceinline__ float sigmoidf_(float x) { return 1.f / (1.f + __expf(-x)); }
__device__ __forceinline__ ushort f2bf_bits(float f) {
    __hip_bfloat16 h = __float2bfloat16(f);
    return *(ushort*)&h;
}

// ---------------- LayerNorm → bf16 output ----------------
__global__ __launch_bounds__(256) void ln_kernel(const float* __restrict__ x,
                                                 const float* __restrict__ g,
                                                 const float* __restrict__ be,
                                                 ushort* __restrict__ hb)
{
    int row = blockIdx.x;
    const float4* xr = (const float4*)(x + (long)row * D_MODEL);
    float4 v = xr[threadIdx.x];
    float s1 = v.x + v.y + v.z + v.w;
    float s2 = v.x*v.x + v.y*v.y + v.z*v.z + v.w*v.w;
    for (int off = 32; off >= 1; off >>= 1) {
        s1 += __shfl_down(s1, off);
        s2 += __shfl_down(s2, off);
    }
    __shared__ float red[8];
    int wid = threadIdx.x >> 6;
    if ((threadIdx.x & 63) == 0) { red[wid] = s1; red[4 + wid] = s2; }
    __syncthreads();
    float mu  = (red[0] + red[1] + red[2] + red[3]) * (1.f / D_MODEL);
    float ex2 = (red[4] + red[5] + red[6] + red[7]) * (1.f / D_MODEL);
    float inv = rsqrtf(ex2 - mu * mu + 1e-5f);
    float4 g4 = ((const float4*)g)[threadIdx.x];
    float4 b4 = ((const float4*)be)[threadIdx.x];
    ushort4 o;
    o.x = f2bf_bits((v.x - mu) * inv * g4.x + b4.x);
    o.y = f2bf_bits((v.y - mu) * inv * g4.y + b4.y);
    o.z = f2bf_bits((v.z - mu) * inv * g4.z + b4.z);
    o.w = f2bf_bits((v.w - mu) * inv * g4.w + b4.w);
    *(ushort4*)(hb + (long)row * D_MODEL + threadIdx.x * 4) = o;
}

// ---------------- f32 [R][C] → bf16 [C][R] transpose (guarded) ----------------
__global__ __launch_bounds__(256) void transpose_bf16_kernel(const float* __restrict__ in,
                                                             ushort* __restrict__ out,
                                                             int R, int C)
{
    __shared__ float tile[64][65];
    int c0 = blockIdx.x * 64, r0 = blockIdx.y * 64;
    #pragma unroll
    for (int i = 0; i < 16; ++i) {
        int idx = threadIdx.x + i * 256;
        int r = idx >> 6, c = idx & 63;
        tile[r][c] = (r0 + r < R && c0 + c < C) ? in[(long)(r0 + r) * C + (c0 + c)] : 0.f;
    }
    __syncthreads();
    #pragma unroll
    for (int i = 0; i < 16; ++i) {
        int idx = threadIdx.x + i * 256;
        int cc = idx >> 6, rr = idx & 63;
        if (c0 + cc < C && r0 + rr < R)
            out[(long)(c0 + cc) * R + (r0 + rr)] = f2bf_bits(tile[rr][cc]);
    }
}

// ---------------- bf16 MFMA GEMM 128x128: C = A[M,K(lda)] * Bt[N,K(ldb)]^T -----------
// blockIdx.z = split-K slice: advances A,Bt by z*K elements and C by z*M*N.
// EPI 0: C = acc ; EPI 1: C = softplus(acc + bias[n]) ; EPI 2: C = acc + resid
template <int EPI>
__global__ __launch_bounds__(256) void gemm_mfma_kernel(const ushort* __restrict__ A,
                                                        const ushort* __restrict__ Bt,
                                                        const float* __restrict__ bias,
                                                        const float* __restrict__ resid,
                                                        float* __restrict__ C,
                                                        int M, int N, int K, int lda, int ldb)
{
    long zoff = (long)blockIdx.z;
    A  += zoff * K;
    Bt += zoff * K;
    C  += zoff * (long)M * N;
    __shared__ __align__(16) ushort Al[128 * 32];
    __shared__ __align__(16) ushort Bl[128 * 32];
    int tid = threadIdx.x;
    int lane = tid & 63;
    int w = tid >> 6, wr = w >> 1, wc = w & 1;
    int m0 = blockIdx.y * 128, n0 = blockIdx.x * 128;
    f32x4 acc[4][4];
    #pragma unroll
    for (int m = 0; m < 4; ++m)
        #pragma unroll
        for (int n = 0; n < 4; ++n) acc[m][n] = (f32x4){0.f, 0.f, 0.f, 0.f};
    int l15 = lane & 15, kq = lane >> 4;

    for (int k0 = 0; k0 < K; k0 += 32) {
        #pragma unroll
        for (int i = 0; i < 2; ++i) {
            int s = i * 256 + tid;
            int row = s >> 2, kg = s & 3;
            int kgl = kg ^ ((row >> 1) & 3);
            __builtin_amdgcn_global_load_lds(
                (const __attribute__((address_space(1))) void*)(A + (long)(m0 + row) * lda + k0 + kgl * 8),
                (__attribute__((address_space(3))) void*)(Al + s * 8), 16, 0, 0);
            __builtin_amdgcn_global_load_lds(
                (const __attribute__((address_space(1))) void*)(Bt + (long)(n0 + row) * ldb + k0 + kgl * 8),
                (__attribute__((address_space(3))) void*)(Bl + s * 8), 16, 0, 0);
        }
        __syncthreads();
        short8 af[4], bf[4];
        #pragma unroll
        for (int m = 0; m < 4; ++m) {
            int row = wr * 64 + m * 16 + l15;
            af[m] = *(const short8*)&Al[row * 32 + (kq ^ ((row >> 1) & 3)) * 8];
        }
        #pragma unroll
        for (int n = 0; n < 4; ++n) {
            int row = wc * 64 + n * 16 + l15;
            bf[n] = *(const short8*)&Bl[row * 32 + (kq ^ ((row >> 1) & 3)) * 8];
        }
        #pragma unroll
        for (int m = 0; m < 4; ++m)
            #pragma unroll
            for (int n = 0; n < 4; ++n)
                acc[m][n] = __builtin_amdgcn_mfma_f32_16x16x32_bf16(af[m], bf[n], acc[m][n], 0, 0, 0);
        __syncthreads();
    }
    #pragma unroll
    for (int m = 0; m < 4; ++m) {
        #pragma unroll
        for (int n = 0; n < 4; ++n) {
            #pragma unroll
            for (int r = 0; r < 4; ++r) {
                int row = m0 + wr * 64 + m * 16 + kq * 4 + r;
                int col = n0 + wc * 64 + n * 16 + l15;
                float v = acc[m][n][r];
                if (EPI == 1) {
                    v += bias[col];
                    v = (v > 20.f) ? v : log1pf(__expf(v));
                } else if (EPI == 2) {
                    v += resid[(long)row * N + col];
                }
                C[(long)row * N + col] = v;
            }
        }
    }
}

// ---------------- bf16 MFMA GEMM 128x64 ----------------
// EPI 0: C = acc ; EPI 1: C = softplus(acc + bias[n]) ; EPI 2: C = acc + resid
template <int EPI>
__global__ __launch_bounds__(256) void gemm_mfma64_kernel(const ushort* __restrict__ A,
                                                          const ushort* __restrict__ Bt,
                                                          const float* __restrict__ bias,
                                                          const float* __restrict__ resid,
                                                          float* __restrict__ C,
                                                          int M, int N, int K)
{
    __shared__ __align__(16) ushort Al[128 * 32];
    __shared__ __align__(16) ushort Bl[64 * 32];
    int tid = threadIdx.x;
    int lane = tid & 63;
    int w = tid >> 6, wr = w >> 1, wc = w & 1;
    int m0 = blockIdx.y * 128, n0 = blockIdx.x * 64;
    f32x4 acc[4][2];
    #pragma unroll
    for (int m = 0; m < 4; ++m)
        #pragma unroll
        for (int n = 0; n < 2; ++n) acc[m][n] = (f32x4){0.f, 0.f, 0.f, 0.f};
    int l15 = lane & 15, kq = lane >> 4;

    for (int k0 = 0; k0 < K; k0 += 32) {
        #pragma unroll
        for (int i = 0; i < 2; ++i) {
            int s = i * 256 + tid;
            int row = s >> 2, kg = s & 3;
            int kgl = kg ^ ((row >> 1) & 3);
            __builtin_amdgcn_global_load_lds(
                (const __attribute__((address_space(1))) void*)(A + (long)(m0 + row) * K + k0 + kgl * 8),
                (__attribute__((address_space(3))) void*)(Al + s * 8), 16, 0, 0);
        }
        {
            int s = tid;
            int row = s >> 2, kg = s & 3;
            int kgl = kg ^ ((row >> 1) & 3);
            __builtin_amdgcn_global_load_lds(
                (const __attribute__((address_space(1))) void*)(Bt + (long)(n0 + row) * K + k0 + kgl * 8),
                (__attribute__((address_space(3))) void*)(Bl + s * 8), 16, 0, 0);
        }
        __syncthreads();
        short8 af[4], bf[2];
        #pragma unroll
        for (int m = 0; m < 4; ++m) {
            int row = wr * 64 + m * 16 + l15;
            af[m] = *(const short8*)&Al[row * 32 + (kq ^ ((row >> 1) & 3)) * 8];
        }
        #pragma unroll
        for (int n = 0; n < 2; ++n) {
            int row = wc * 32 + n * 16 + l15;
            bf[n] = *(const short8*)&Bl[row * 32 + (kq ^ ((row >> 1) & 3)) * 8];
        }
        #pragma unroll
        for (int m = 0; m < 4; ++m)
            #pragma unroll
            for (int n = 0; n < 2; ++n)
                acc[m][n] = __builtin_amdgcn_mfma_f32_16x16x32_bf16(af[m], bf[n], acc[m][n], 0, 0, 0);
        __syncthreads();
    }
    #pragma unroll
    for (int m = 0; m < 4; ++m) {
        #pragma unroll
        for (int n = 0; n < 2; ++n) {
            #pragma unroll
            for (int r = 0; r < 4; ++r) {
                int row = m0 + wr * 64 + m * 16 + kq * 4 + r;
                int col = n0 + wc * 32 + n * 16 + l15;
                float v = acc[m][n][r];
                if (EPI == 1) {
                    v += bias[col];
                    v = (v > 20.f) ? v : log1pf(__expf(v));
                } else if (EPI == 2) {
                    v += resid[(long)row * N + col];
                }
                C[(long)row * N + col] = v;
            }
        }
    }
}

// -------- out_proj split-K reduce: out = sum_k Ppart[k] + resid --------
__global__ __launch_bounds__(256) void reduce_out_kernel(const float* __restrict__ Ppart,
                                                         const float* __restrict__ resid,
                                                         float* __restrict__ out)
{
    long i = (long)blockIdx.x * 256 + threadIdx.x;   // over NTOK*D_MODEL/4
    const long STRIDE = (long)NTOK * D_MODEL / 4;
    float4 s = ((const float4*)Ppart)[i];
    #pragma unroll
    for (int k = 1; k < OP_SPLITK; ++k) {
        float4 p = ((const float4*)Ppart)[k * STRIDE + i];
        s.x += p.x; s.y += p.y; s.z += p.z; s.w += p.w;
    }
    float4 r = ((const float4*)resid)[i];
    s.x += r.x; s.y += r.y; s.z += r.z; s.w += r.w;
    ((float4*)out)[i] = s;
}

// -------- split-K bf16 MFMA GEMM for xpj --------
__global__ __launch_bounds__(256) void gemm4_mfma_kernel(const ushort* __restrict__ A,
                                                         const ushort* __restrict__ Bt,
                                                         float* __restrict__ Ppart,
                                                         int M, int K)
{
    __shared__ __align__(16) ushort Al[64 * 32];
    __shared__ __align__(16) ushort Bl[160 * 32];
    int tid = threadIdx.x;
    int lane = tid & 63;
    int w = tid >> 6, wr = w >> 1, wc = w & 1;
    int sk = blockIdx.x;
    int m0 = blockIdx.y * 64;
    int kbase = sk * (K / SPLITK);
    f32x4 acc[2][5];
    #pragma unroll
    for (int m = 0; m < 2; ++m)
        #pragma unroll
        for (int n = 0; n < 5; ++n) acc[m][n] = (f32x4){0.f, 0.f, 0.f, 0.f};
    int l15 = lane & 15, kq = lane >> 4;

    for (int ks = 0; ks < K / SPLITK; ks += 32) {
        int k0 = kbase + ks;
        {
            int s = tid;
            int row = s >> 2, kg = s & 3;
            int kgl = kg ^ ((row >> 1) & 3);
            __builtin_amdgcn_global_load_lds(
                (const __attribute__((address_space(1))) void*)(A + (long)(m0 + row) * K + k0 + kgl * 8),
                (__attribute__((address_space(3))) void*)(Al + s * 8), 16, 0, 0);
        }
        #pragma unroll
        for (int i = 0; i < 3; ++i) {
            int s = i * 256 + tid;
            if (s < 640) {
                int row = s >> 2, kg = s & 3;
                int kgl = kg ^ ((row >> 1) & 3);
                __builtin_amdgcn_global_load_lds(
                    (const __attribute__((address_space(1))) void*)(Bt + (long)row * K + k0 + kgl * 8),
                    (__attribute__((address_space(3))) void*)(Bl + s * 8), 16, 0, 0);
            }
        }
        __syncthreads();
        short8 af[2], bf[5];
        #pragma unroll
        for (int m = 0; m < 2; ++m) {
            int row = wr * 32 + m * 16 + l15;
            af[m] = *(const short8*)&Al[row * 32 + (kq ^ ((row >> 1) & 3)) * 8];
        }
        #pragma unroll
        for (int n = 0; n < 5; ++n) {
            int row = wc * 80 + n * 16 + l15;
            bf[n] = *(const short8*)&Bl[row * 32 + (kq ^ ((row >> 1) & 3)) * 8];
        }
        #pragma unroll
        for (int m = 0; m < 2; ++m)
            #pragma unroll
            for (int n = 0; n < 5; ++n)
                acc[m][n] = __builtin_amdgcn_mfma_f32_16x16x32_bf16(af[m], bf[n], acc[m][n], 0, 0, 0);
        __syncthreads();
    }
    float* P = Ppart + (long)sk * M * XPJ_N;
    #pragma unroll
    for (int m = 0; m < 2; ++m) {
        #pragma unroll
        for (int n = 0; n < 5; ++n) {
            #pragma unroll
            for (int r = 0; r < 4; ++r) {
                int row = m0 + wr * 32 + m * 16 + kq * 4 + r;
                int col = wc * 80 + n * 16 + l15;
                P[(long)row * XPJ_N + col] = acc[m][n][r];
            }
        }
    }
}

// -------- reduce split-K partials → xpj f32 + dt_r bf16 --------
__global__ __launch_bounds__(256) void reduce_xpj_kernel(const float* __restrict__ Ppart,
                                                         float* __restrict__ xpj,
                                                         ushort* __restrict__ dtr)
{
    long i = (long)blockIdx.x * 256 + threadIdx.x;   // over NTOK*XPJ_N
    float s = 0.f;
    #pragma unroll
    for (int k = 0; k < SPLITK; ++k) s += Ppart[k * (long)NTOK * XPJ_N + i];
    xpj[i] = s;
    int col = (int)(i % XPJ_N);
    long row = i / XPJ_N;
    if (col < DT_RANK) dtr[row * DT_RANK + col] = f2bf_bits(s);
}

// ---------------- depthwise causal conv (width 4) + bias + SiLU; f32 + bf16 out -------
__global__ __launch_bounds__(256) void conv_silu_kernel(const float* __restrict__ xz,
                                                        const float* __restrict__ cw,
                                                        const float* __restrict__ cb,
                                                        float* __restrict__ xb,
                                                        ushort* __restrict__ xbb)
{
    long i = (long)blockIdx.x * 256 + threadIdx.x;  // over NTOK*D_INNER
    int d = (int)(i & (D_INNER - 1));
    long tok = i >> 11;
    int l = (int)(tok & (SEQLEN - 1));
    float w0 = cw[d * 4 + 0], w1 = cw[d * 4 + 1], w2 = cw[d * 4 + 2], w3 = cw[d * 4 + 3];
    float acc = cb[d];
    acc += xz[tok * NPROJ + d] * w3;
    if (l >= 1) acc += xz[(tok - 1) * NPROJ + d] * w2;
    if (l >= 2) acc += xz[(tok - 2) * NPROJ + d] * w1;
    if (l >= 3) acc += xz[(tok - 3) * NPROJ + d] * w0;
    float v = acc * sigmoidf_(acc);
    xb[i] = v;
    xbb[i] = f2bf_bits(v);
}

// ======================= chunked selective scan (4 lanes/channel, CHUNK=32) ==========
__global__ __launch_bounds__(256) void scan_partial_kernel(const float* __restrict__ delta,
                                                           const float* __restrict__ xb,
                                                           const float* __restrict__ xpj,
                                                           const float* __restrict__ A_log,
                                                           float* __restrict__ Pout,
                                                           float* __restrict__ Hout)
{
    int tid = threadIdx.x;
    int j = tid & 3, grp = tid >> 2;
    long gidx = (long)blockIdx.x * 64 + grp;      // over BATCH*NCHUNK*D_INNER
    int d = (int)(gidx & (D_INNER - 1));
    int c = (int)((gidx >> 11) & (NCHUNK - 1));
    int b = (int)(gidx >> (11 + LOG2_NCHUNK));
    float4 al = *(const float4*)&A_log[d * D_STATE + 4 * j];
    float a0 = -__expf(al.x), a1 = -__expf(al.y), a2 = -__expf(al.z), a3 = -__expf(al.w);
    float h0 = 0.f, h1 = 0.f, h2 = 0.f, h3 = 0.f, cum = 0.f;
    long tok0 = (long)b * SEQLEN + c * CHUNK;
    const float* dp = delta + tok0 * D_INNER + d;
    const float* xp = xb + tok0 * D_INNER + d;
    const float* Bp = xpj + tok0 * XPJ_N + DT_RANK + 4 * j;
    for (int t = 0; t < CHUNK; ++t) {
        float dl = *dp;
        float x  = *xp;
        float4 Bv = *(const float4*)Bp;
        dp += D_INNER; xp += D_INNER; Bp += XPJ_N;
        cum += dl;
        float ux = dl * x;
        h0 = __expf(dl * a0) * h0 + ux * Bv.x;
        h1 = __expf(dl * a1) * h1 + ux * Bv.y;
        h2 = __expf(dl * a2) * h2 + ux * Bv.z;
        h3 = __expf(dl * a3) * h3 + ux * Bv.w;
    }
    long o = gidx * D_STATE + 4 * j;
    *(float4*)&Pout[o] = (float4){__expf(a0 * cum), __expf(a1 * cum), __expf(a2 * cum), __expf(a3 * cum)};
    *(float4*)&Hout[o] = (float4){h0, h1, h2, h3};
}

__global__ __launch_bounds__(256) void scan_chunkscan_kernel(const float* __restrict__ P,
                                                             const float* __restrict__ H,
                                                             float* __restrict__ hinit)
{
    long i = (long)blockIdx.x * 256 + threadIdx.x;  // over BATCH*D_INNER*D_STATE
    int n = (int)(i & (D_STATE - 1));
    int d = (int)((i >> 4) & (D_INNER - 1));
    int b = (int)(i >> 15);
    float h = 0.f;
    for (int c = 0; c < NCHUNK; ++c) {
        long o = ((((long)b * NCHUNK + c) * D_INNER + d) * D_STATE) + n;
        hinit[o] = h;
        h = P[o] * h + H[o];
    }
}

__global__ __launch_bounds__(256) void scan_final_kernel(const float* __restrict__ delta,
                                                         const float* __restrict__ xb,
                                                         const float* __restrict__ xpj,
                                                         const float* __restrict__ xz,
                                                         const float* __restrict__ A_log,
                                                         const float* __restrict__ Dp,
                                                         const float* __restrict__ hinit,
                                                         ushort* __restrict__ yb)
{
    int tid = threadIdx.x;
    int j = tid & 3, grp = tid >> 2;
    long gidx = (long)blockIdx.x * 64 + grp;
    int d = (int)(gidx & (D_INNER - 1));
    int c = (int)((gidx >> 11) & (NCHUNK - 1));
    int b = (int)(gidx >> (11 + LOG2_NCHUNK));
    float4 al = *(const float4*)&A_log[d * D_STATE + 4 * j];
    float a0 = -__expf(al.x), a1 = -__expf(al.y), a2 = -__expf(al.z), a3 = -__expf(al.w);
    float dpar = Dp[d];
    float4 hv = *(const float4*)&hinit[gidx * D_STATE + 4 * j];
    float h0 = hv.x, h1 = hv.y, h2 = hv.z, h3 = hv.w;
    long tok0 = (long)b * SEQLEN + c * CHUNK;
    const float* dp = delta + tok0 * D_INNER + d;
    const float* xp = xb + tok0 * D_INNER + d;
    const float* Bp = xpj + tok0 * XPJ_N + DT_RANK + 4 * j;
    const float* Cp = Bp + D_STATE;
    const float* zp = xz + tok0 * NPROJ + D_INNER + d;
    ushort* yp = yb + tok0 * D_INNER + d;
    for (int t = 0; t < CHUNK; ++t) {
        float dl = *dp;
        float x  = *xp;
        float4 Bv = *(const float4*)Bp;
        float4 Cv = *(const float4*)Cp;
        dp += D_INNER; xp += D_INNER; Bp += XPJ_N; Cp += XPJ_N;
        float ux = dl * x;
        h0 = __expf(dl * a0) * h0 + ux * Bv.x;
        h1 = __expf(dl * a1) * h1 + ux * Bv.y;
        h2 = __expf(dl * a2) * h2 + ux * Bv.z;
        h3 = __expf(dl * a3) * h3 + ux * Bv.w;
        float p = h0 * Cv.x + h1 * Cv.y + h2 * Cv.z + h3 * Cv.w;
        p += __shfl_xor(p, 1);
        p += __shfl_xor(p, 2);
        if (j == 0) {
            float z = *zp;
            float y = p + x * dpar;
            *yp = f2bf_bits(y * (z * sigmoidf_(z)));
        }
        zp += NPROJ; yp += D_INNER;
    }
}

extern "C" void kernel_launch(void* const* d_in, const int* in_sizes, int n_in,
                              void* d_out, int out_size, void* d_ws, size_t ws_size,
                              hipStream_t stream) {
    const float* x         = (const float*)d_in[0];
    const float* ln_gamma  = (const float*)d_in[1];
    const float* ln_beta   = (const float*)d_in[2];
    const float* in_proj_w = (const float*)d_in[3];
    const float* conv_w    = (const float*)d_in[4];
    const float* conv_b    = (const float*)d_in[5];
    const float* x_proj_w  = (const float*)d_in[6];
    const float* dt_proj_w = (const float*)d_in[7];
    const float* dt_proj_b = (const float*)d_in[8];
    const float* A_log     = (const float*)d_in[9];
    const float* D_param   = (const float*)d_in[10];
    const float* out_proj_w= (const float*)d_in[11];
    float* out = (float*)d_out;

    float* ws = (float*)d_ws;
    float* h     = ws;                               // 2,097,152 floats
    float* xz    = h     + (long)NTOK * D_MODEL;     // 8,388,608
    float* xb    = xz    + (long)NTOK * NPROJ;       // 4,194,304
    float* xpj   = xb    + (long)NTOK * D_INNER;     //   327,680
    float* delta = xpj   + (long)NTOK * XPJ_N;       // 4,194,304
    float* yfin  = delta + (long)NTOK * D_INNER;     // 4,194,304

    const long PH = (long)BATCH * NCHUNK * D_INNER * D_STATE;   // 2,097,152 floats
    // Aliased scratch, lifetimes stream-ordered:
    ushort* h_bf16  = (ushort*)h;              // dead after gemm2
    ushort* DTT     = (ushort*)h;              // dt_proj_w^T bf16; 3b → gemm5
    float*  hinit   = h;                       // chunkscan → scan_final (exactly fills h slot)
    ushort* W2T     = (ushort*)xb;             // dead after gemm2 (conv overwrites)
    ushort* xb_bf16 = (ushort*)delta;          // conv → gemm4 (gemm5 then overwrites delta)
    ushort* XPT     = (ushort*)xpj;            // x_proj_w^T bf16; dead after gemm4
    float*  Ppart   = yfin;                    // [8][2048][160]; dead after reduce
    ushort* dtr     = (ushort*)(yfin + (long)SPLITK * NTOK * XPJ_N); // reduce → gemm5
    float*  Pbuf    = yfin;                    // scan P   [PH]
    float*  Hbuf    = yfin + PH;               // scan H   [PH]
    ushort* y_bf16  = (ushort*)yfin;           // scan_final out (Pbuf dead after chunkscan)
    ushort* W7T     = (ushort*)xz;             // after scan_final (xz dead)
    float*  PpartO  = xb;                      // out_proj split-K partials [4][2048][1024]
                                               // = 8,388,608 f in xb+xpj+delta span (all dead
                                               // after scan_final; span = 8,716,288 f) ✓

    // 0a. W2T = in_proj_w^T bf16 [4096][1024]
    transpose_bf16_kernel<<<dim3(NPROJ / 64, D_MODEL / 64), 256, 0, stream>>>(
        in_proj_w, W2T, D_MODEL, NPROJ);

    // 1. LayerNorm → bf16
    ln_kernel<<<NTOK, 256, 0, stream>>>(x, ln_gamma, ln_beta, h_bf16);

    // 2. xz = h @ in_proj_w (MFMA) [2048,1024]x[1024,4096]
    gemm_mfma_kernel<0><<<dim3(NPROJ / 128, NTOK / 128), 256, 0, stream>>>(
        h_bf16, W2T, nullptr, nullptr, xz, NTOK, NPROJ, D_MODEL, D_MODEL, D_MODEL);

    // 3. conv4 + bias + SiLU → xb f32 + bf16
    conv_silu_kernel<<<(NTOK * D_INNER) / 256, 256, 0, stream>>>(
        xz, conv_w, conv_b, xb, xb_bf16);

    // 3b. XPT = x_proj_w^T ; DTT = dt_proj_w^T
    transpose_bf16_kernel<<<dim3((XPJ_N + 63) / 64, D_INNER / 64), 256, 0, stream>>>(
        x_proj_w, XPT, D_INNER, XPJ_N);
    transpose_bf16_kernel<<<dim3(D_INNER / 64, DT_RANK / 64), 256, 0, stream>>>(
        dt_proj_w, DTT, DT_RANK, D_INNER);

    // 4. xpj partials (split-K MFMA) then reduce
    gemm4_mfma_kernel<<<dim3(SPLITK, NTOK / 64), 256, 0, stream>>>(
        xb_bf16, XPT, Ppart, NTOK, D_INNER);
    reduce_xpj_kernel<<<(NTOK * XPJ_N) / 256, 256, 0, stream>>>(Ppart, xpj, dtr);

    // 5. delta = softplus(dt_r @ dt_proj_w + b) (MFMA 128x64, 512 blocks)
    gemm_mfma64_kernel<1><<<dim3(D_INNER / 64, NTOK / 128), 256, 0, stream>>>(
        dtr, DTT, dt_proj_b, nullptr, delta, NTOK, D_INNER, DT_RANK);

    // 6. chunked selective scan (4 lanes/channel, CHUNK=32)
    scan_partial_kernel<<<(BATCH * NCHUNK * D_INNER) / 64, 256, 0, stream>>>(
        delta, xb, xpj, A_log, Pbuf, Hbuf);
    scan_chunkscan_kernel<<<(BATCH * D_INNER * D_STATE) / 256, 256, 0, stream>>>(
        Pbuf, Hbuf, hinit);
    scan_final_kernel<<<(BATCH * NCHUNK * D_INNER) / 64, 256, 0, stream>>>(
        delta, xb, xpj, xz, A_log, D_param, hinit, y_bf16);

    // 6b. W7T = out_proj_w^T bf16 (xz dead)
    transpose_bf16_kernel<<<dim3(D_MODEL / 64, D_INNER / 64), 256, 0, stream>>>(
        out_proj_w, W7T, D_INNER, D_MODEL);

    // 7. out_proj split-K=4: partials then fused reduce+residual
    //    each z-slice: [2048,512]x[512,1024] → PpartO[z]
    gemm_mfma_kernel<0><<<dim3(D_MODEL / 128, NTOK / 128, OP_SPLITK), 256, 0, stream>>>(
        y_bf16, W7T, nullptr, nullptr, PpartO, NTOK, D_MODEL, D_INNER / OP_SPLITK,
        D_INNER, D_INNER);
    reduce_out_kernel<<<(NTOK * D_MODEL / 4) / 256, 256, 0, stream>>>(PpartO, x, out);
}

// Round 9
// 203.908 us; speedup vs baseline: 7.9051x; 1.0239x over previous
//
#include <hip/hip_runtime.h>
#include <hip/hip_bf16.h>

#define D_MODEL 1024
#define D_INNER 2048
#define NPROJ   4096   /* 2*D_INNER */
#define D_STATE 16
#define DT_RANK 128
#define XPJ_N   160    /* DT_RANK + 2*D_STATE */
#define SEQLEN  1024
#define BATCH   2
#define NTOK    2048   /* BATCH*SEQLEN */
#define CHUNK   32
#define NCHUNK  (SEQLEN / CHUNK)   /* 32 */
#define LOG2_NCHUNK 5
#define SPLITK  8      /* gemm4 split */
#define OP_SPLITK 4    /* out_proj split */

typedef short short8 __attribute__((ext_vector_type(8)));
typedef float f32x4 __attribute__((ext_vector_type(4)));

__device__ __forceinline__ float sigmoidf_(float x) { return 1.f / (1.f + __expf(-x)); }
__device__ __forceinline__ ushort f2bf_bits(float f) {
    __hip_bfloat16 h = __float2bfloat16(f);
    return *(ushort*)&h;
}
__device__ __forceinline__ float bf2f(ushort u) {
    union { unsigned int i; float f; } v;
    v.i = ((unsigned int)u) << 16;
    return v.f;
}

// ---------------- LayerNorm → bf16 output ----------------
__global__ __launch_bounds__(256) void ln_kernel(const float* __restrict__ x,
                                                 const float* __restrict__ g,
                                                 const float* __restrict__ be,
                                                 ushort* __restrict__ hb)
{
    int row = blockIdx.x;
    const float4* xr = (const float4*)(x + (long)row * D_MODEL);
    float4 v = xr[threadIdx.x];
    float s1 = v.x + v.y + v.z + v.w;
    float s2 = v.x*v.x + v.y*v.y + v.z*v.z + v.w*v.w;
    for (int off = 32; off >= 1; off >>= 1) {
        s1 += __shfl_down(s1, off);
        s2 += __shfl_down(s2, off);
    }
    __shared__ float red[8];
    int wid = threadIdx.x >> 6;
    if ((threadIdx.x & 63) == 0) { red[wid] = s1; red[4 + wid] = s2; }
    __syncthreads();
    float mu  = (red[0] + red[1] + red[2] + red[3]) * (1.f / D_MODEL);
    float ex2 = (red[4] + red[5] + red[6] + red[7]) * (1.f / D_MODEL);
    float inv = rsqrtf(ex2 - mu * mu + 1e-5f);
    float4 g4 = ((const float4*)g)[threadIdx.x];
    float4 b4 = ((const float4*)be)[threadIdx.x];
    ushort4 o;
    o.x = f2bf_bits((v.x - mu) * inv * g4.x + b4.x);
    o.y = f2bf_bits((v.y - mu) * inv * g4.y + b4.y);
    o.z = f2bf_bits((v.z - mu) * inv * g4.z + b4.z);
    o.w = f2bf_bits((v.w - mu) * inv * g4.w + b4.w);
    *(ushort4*)(hb + (long)row * D_MODEL + threadIdx.x * 4) = o;
}

// ---------------- f32 [R][C] → bf16 [C][R] transpose (guarded) ----------------
__global__ __launch_bounds__(256) void transpose_bf16_kernel(const float* __restrict__ in,
                                                             ushort* __restrict__ out,
                                                             int R, int C)
{
    __shared__ float tile[64][65];
    int c0 = blockIdx.x * 64, r0 = blockIdx.y * 64;
    #pragma unroll
    for (int i = 0; i < 16; ++i) {
        int idx = threadIdx.x + i * 256;
        int r = idx >> 6, c = idx & 63;
        tile[r][c] = (r0 + r < R && c0 + c < C) ? in[(long)(r0 + r) * C + (c0 + c)] : 0.f;
    }
    __syncthreads();
    #pragma unroll
    for (int i = 0; i < 16; ++i) {
        int idx = threadIdx.x + i * 256;
        int cc = idx >> 6, rr = idx & 63;
        if (c0 + cc < C && r0 + rr < R)
            out[(long)(c0 + cc) * R + (r0 + rr)] = f2bf_bits(tile[rr][cc]);
    }
}

// ---------------- bf16 MFMA GEMM 128x128: C = A[M,K(lda)] * Bt[N,K(ldb)]^T -----------
// blockIdx.z advances A,Bt by z*K and C by z*M*N (split-K).
// EPI 0: v=acc ; EPI 1: v=softplus(acc+bias[n]) ; EPI 2: v=acc+resid
// OBF 0: store f32 to Cf ; OBF 1: store bf16 to Cb
template <int EPI, int OBF>
__global__ __launch_bounds__(256) void gemm_mfma_kernel(const ushort* __restrict__ A,
                                                        const ushort* __restrict__ Bt,
                                                        const float* __restrict__ bias,
                                                        const float* __restrict__ resid,
                                                        float* __restrict__ Cf,
                                                        ushort* __restrict__ Cb,
                                                        int M, int N, int K, int lda, int ldb)
{
    long zoff = (long)blockIdx.z;
    A  += zoff * K;
    Bt += zoff * K;
    if (OBF == 0) Cf += zoff * (long)M * N;
    __shared__ __align__(16) ushort Al[128 * 32];
    __shared__ __align__(16) ushort Bl[128 * 32];
    int tid = threadIdx.x;
    int lane = tid & 63;
    int w = tid >> 6, wr = w >> 1, wc = w & 1;
    int m0 = blockIdx.y * 128, n0 = blockIdx.x * 128;
    f32x4 acc[4][4];
    #pragma unroll
    for (int m = 0; m < 4; ++m)
        #pragma unroll
        for (int n = 0; n < 4; ++n) acc[m][n] = (f32x4){0.f, 0.f, 0.f, 0.f};
    int l15 = lane & 15, kq = lane >> 4;

    for (int k0 = 0; k0 < K; k0 += 32) {
        #pragma unroll
        for (int i = 0; i < 2; ++i) {
            int s = i * 256 + tid;
            int row = s >> 2, kg = s & 3;
            int kgl = kg ^ ((row >> 1) & 3);
            __builtin_amdgcn_global_load_lds(
                (const __attribute__((address_space(1))) void*)(A + (long)(m0 + row) * lda + k0 + kgl * 8),
                (__attribute__((address_space(3))) void*)(Al + s * 8), 16, 0, 0);
            __builtin_amdgcn_global_load_lds(
                (const __attribute__((address_space(1))) void*)(Bt + (long)(n0 + row) * ldb + k0 + kgl * 8),
                (__attribute__((address_space(3))) void*)(Bl + s * 8), 16, 0, 0);
        }
        __syncthreads();
        short8 af[4], bf[4];
        #pragma unroll
        for (int m = 0; m < 4; ++m) {
            int row = wr * 64 + m * 16 + l15;
            af[m] = *(const short8*)&Al[row * 32 + (kq ^ ((row >> 1) & 3)) * 8];
        }
        #pragma unroll
        for (int n = 0; n < 4; ++n) {
            int row = wc * 64 + n * 16 + l15;
            bf[n] = *(const short8*)&Bl[row * 32 + (kq ^ ((row >> 1) & 3)) * 8];
        }
        #pragma unroll
        for (int m = 0; m < 4; ++m)
            #pragma unroll
            for (int n = 0; n < 4; ++n)
                acc[m][n] = __builtin_amdgcn_mfma_f32_16x16x32_bf16(af[m], bf[n], acc[m][n], 0, 0, 0);
        __syncthreads();
    }
    #pragma unroll
    for (int m = 0; m < 4; ++m) {
        #pragma unroll
        for (int n = 0; n < 4; ++n) {
            #pragma unroll
            for (int r = 0; r < 4; ++r) {
                int row = m0 + wr * 64 + m * 16 + kq * 4 + r;
                int col = n0 + wc * 64 + n * 16 + l15;
                float v = acc[m][n][r];
                if (EPI == 1) {
                    v += bias[col];
                    v = (v > 20.f) ? v : log1pf(__expf(v));
                } else if (EPI == 2) {
                    v += resid[(long)row * N + col];
                }
                if (OBF) Cb[(long)row * N + col] = f2bf_bits(v);
                else     Cf[(long)row * N + col] = v;
            }
        }
    }
}

// ---------------- bf16 MFMA GEMM 128x64 ----------------
template <int EPI, int OBF>
__global__ __launch_bounds__(256) void gemm_mfma64_kernel(const ushort* __restrict__ A,
                                                          const ushort* __restrict__ Bt,
                                                          const float* __restrict__ bias,
                                                          const float* __restrict__ resid,
                                                          float* __restrict__ Cf,
                                                          ushort* __restrict__ Cb,
                                                          int M, int N, int K)
{
    __shared__ __align__(16) ushort Al[128 * 32];
    __shared__ __align__(16) ushort Bl[64 * 32];
    int tid = threadIdx.x;
    int lane = tid & 63;
    int w = tid >> 6, wr = w >> 1, wc = w & 1;
    int m0 = blockIdx.y * 128, n0 = blockIdx.x * 64;
    f32x4 acc[4][2];
    #pragma unroll
    for (int m = 0; m < 4; ++m)
        #pragma unroll
        for (int n = 0; n < 2; ++n) acc[m][n] = (f32x4){0.f, 0.f, 0.f, 0.f};
    int l15 = lane & 15, kq = lane >> 4;

    for (int k0 = 0; k0 < K; k0 += 32) {
        #pragma unroll
        for (int i = 0; i < 2; ++i) {
            int s = i * 256 + tid;
            int row = s >> 2, kg = s & 3;
            int kgl = kg ^ ((row >> 1) & 3);
            __builtin_amdgcn_global_load_lds(
                (const __attribute__((address_space(1))) void*)(A + (long)(m0 + row) * K + k0 + kgl * 8),
                (__attribute__((address_space(3))) void*)(Al + s * 8), 16, 0, 0);
        }
        {
            int s = tid;
            int row = s >> 2, kg = s & 3;
            int kgl = kg ^ ((row >> 1) & 3);
            __builtin_amdgcn_global_load_lds(
                (const __attribute__((address_space(1))) void*)(Bt + (long)(n0 + row) * K + k0 + kgl * 8),
                (__attribute__((address_space(3))) void*)(Bl + s * 8), 16, 0, 0);
        }
        __syncthreads();
        short8 af[4], bf[2];
        #pragma unroll
        for (int m = 0; m < 4; ++m) {
            int row = wr * 64 + m * 16 + l15;
            af[m] = *(const short8*)&Al[row * 32 + (kq ^ ((row >> 1) & 3)) * 8];
        }
        #pragma unroll
        for (int n = 0; n < 2; ++n) {
            int row = wc * 32 + n * 16 + l15;
            bf[n] = *(const short8*)&Bl[row * 32 + (kq ^ ((row >> 1) & 3)) * 8];
        }
        #pragma unroll
        for (int m = 0; m < 4; ++m)
            #pragma unroll
            for (int n = 0; n < 2; ++n)
                acc[m][n] = __builtin_amdgcn_mfma_f32_16x16x32_bf16(af[m], bf[n], acc[m][n], 0, 0, 0);
        __syncthreads();
    }
    #pragma unroll
    for (int m = 0; m < 4; ++m) {
        #pragma unroll
        for (int n = 0; n < 2; ++n) {
            #pragma unroll
            for (int r = 0; r < 4; ++r) {
                int row = m0 + wr * 64 + m * 16 + kq * 4 + r;
                int col = n0 + wc * 32 + n * 16 + l15;
                float v = acc[m][n][r];
                if (EPI == 1) {
                    v += bias[col];
                    v = (v > 20.f) ? v : log1pf(__expf(v));
                } else if (EPI == 2) {
                    v += resid[(long)row * N + col];
                }
                if (OBF) Cb[(long)row * N + col] = f2bf_bits(v);
                else     Cf[(long)row * N + col] = v;
            }
        }
    }
}

// -------- out_proj split-K reduce: out = sum_k Ppart[k] + resid --------
__global__ __launch_bounds__(256) void reduce_out_kernel(const float* __restrict__ Ppart,
                                                         const float* __restrict__ resid,
                                                         float* __restrict__ out)
{
    long i = (long)blockIdx.x * 256 + threadIdx.x;   // over NTOK*D_MODEL/4
    const long STRIDE = (long)NTOK * D_MODEL / 4;
    float4 s = ((const float4*)Ppart)[i];
    #pragma unroll
    for (int k = 1; k < OP_SPLITK; ++k) {
        float4 p = ((const float4*)Ppart)[k * STRIDE + i];
        s.x += p.x; s.y += p.y; s.z += p.z; s.w += p.w;
    }
    float4 r = ((const float4*)resid)[i];
    s.x += r.x; s.y += r.y; s.z += r.z; s.w += r.w;
    ((float4*)out)[i] = s;
}

// -------- split-K bf16 MFMA GEMM for xpj --------
__global__ __launch_bounds__(256) void gemm4_mfma_kernel(const ushort* __restrict__ A,
                                                         const ushort* __restrict__ Bt,
                                                         float* __restrict__ Ppart,
                                                         int M, int K)
{
    __shared__ __align__(16) ushort Al[64 * 32];
    __shared__ __align__(16) ushort Bl[160 * 32];
    int tid = threadIdx.x;
    int lane = tid & 63;
    int w = tid >> 6, wr = w >> 1, wc = w & 1;
    int sk = blockIdx.x;
    int m0 = blockIdx.y * 64;
    int kbase = sk * (K / SPLITK);
    f32x4 acc[2][5];
    #pragma unroll
    for (int m = 0; m < 2; ++m)
        #pragma unroll
        for (int n = 0; n < 5; ++n) acc[m][n] = (f32x4){0.f, 0.f, 0.f, 0.f};
    int l15 = lane & 15, kq = lane >> 4;

    for (int ks = 0; ks < K / SPLITK; ks += 32) {
        int k0 = kbase + ks;
        {
            int s = tid;
            int row = s >> 2, kg = s & 3;
            int kgl = kg ^ ((row >> 1) & 3);
            __builtin_amdgcn_global_load_lds(
                (const __attribute__((address_space(1))) void*)(A + (long)(m0 + row) * K + k0 + kgl * 8),
                (__attribute__((address_space(3))) void*)(Al + s * 8), 16, 0, 0);
        }
        #pragma unroll
        for (int i = 0; i < 3; ++i) {
            int s = i * 256 + tid;
            if (s < 640) {
                int row = s >> 2, kg = s & 3;
                int kgl = kg ^ ((row >> 1) & 3);
                __builtin_amdgcn_global_load_lds(
                    (const __attribute__((address_space(1))) void*)(Bt + (long)row * K + k0 + kgl * 8),
                    (__attribute__((address_space(3))) void*)(Bl + s * 8), 16, 0, 0);
            }
        }
        __syncthreads();
        short8 af[2], bf[5];
        #pragma unroll
        for (int m = 0; m < 2; ++m) {
            int row = wr * 32 + m * 16 + l15;
            af[m] = *(const short8*)&Al[row * 32 + (kq ^ ((row >> 1) & 3)) * 8];
        }
        #pragma unroll
        for (int n = 0; n < 5; ++n) {
            int row = wc * 80 + n * 16 + l15;
            bf[n] = *(const short8*)&Bl[row * 32 + (kq ^ ((row >> 1) & 3)) * 8];
        }
        #pragma unroll
        for (int m = 0; m < 2; ++m)
            #pragma unroll
            for (int n = 0; n < 5; ++n)
                acc[m][n] = __builtin_amdgcn_mfma_f32_16x16x32_bf16(af[m], bf[n], acc[m][n], 0, 0, 0);
        __syncthreads();
    }
    float* P = Ppart + (long)sk * M * XPJ_N;
    #pragma unroll
    for (int m = 0; m < 2; ++m) {
        #pragma unroll
        for (int n = 0; n < 5; ++n) {
            #pragma unroll
            for (int r = 0; r < 4; ++r) {
                int row = m0 + wr * 32 + m * 16 + kq * 4 + r;
                int col = wc * 80 + n * 16 + l15;
                P[(long)row * XPJ_N + col] = acc[m][n][r];
            }
        }
    }
}

// -------- reduce split-K partials → xpj f32 + dt_r bf16 --------
__global__ __launch_bounds__(256) void reduce_xpj_kernel(const float* __restrict__ Ppart,
                                                         float* __restrict__ xpj,
                                                         ushort* __restrict__ dtr)
{
    long i = (long)blockIdx.x * 256 + threadIdx.x;   // over NTOK*XPJ_N
    float s = 0.f;
    #pragma unroll
    for (int k = 0; k < SPLITK; ++k) s += Ppart[k * (long)NTOK * XPJ_N + i];
    xpj[i] = s;
    int col = (int)(i % XPJ_N);
    long row = i / XPJ_N;
    if (col < DT_RANK) dtr[row * DT_RANK + col] = f2bf_bits(s);
}

// ---------------- depthwise causal conv (width 4) + bias + SiLU; bf16 in/out ----------
__global__ __launch_bounds__(256) void conv_silu_kernel(const ushort* __restrict__ xzb,
                                                        const float* __restrict__ cw,
                                                        const float* __restrict__ cb,
                                                        ushort* __restrict__ xbb)
{
    long i = (long)blockIdx.x * 256 + threadIdx.x;  // over NTOK*D_INNER
    int d = (int)(i & (D_INNER - 1));
    long tok = i >> 11;
    int l = (int)(tok & (SEQLEN - 1));
    float w0 = cw[d * 4 + 0], w1 = cw[d * 4 + 1], w2 = cw[d * 4 + 2], w3 = cw[d * 4 + 3];
    float acc = cb[d];
    acc += bf2f(xzb[tok * NPROJ + d]) * w3;
    if (l >= 1) acc += bf2f(xzb[(tok - 1) * NPROJ + d]) * w2;
    if (l >= 2) acc += bf2f(xzb[(tok - 2) * NPROJ + d]) * w1;
    if (l >= 3) acc += bf2f(xzb[(tok - 3) * NPROJ + d]) * w0;
    float v = acc * sigmoidf_(acc);
    xbb[i] = f2bf_bits(v);
}

// ======================= chunked selective scan (4 lanes/channel, CHUNK=32) ==========
// delta, xb bf16; B,C f32; z bf16.
__global__ __launch_bounds__(256) void scan_partial_kernel(const ushort* __restrict__ deltab,
                                                           const ushort* __restrict__ xbb,
                                                           const float* __restrict__ xpj,
                                                           const float* __restrict__ A_log,
                                                           float* __restrict__ Pout,
                                                           float* __restrict__ Hout)
{
    int tid = threadIdx.x;
    int j = tid & 3, grp = tid >> 2;
    long gidx = (long)blockIdx.x * 64 + grp;      // over BATCH*NCHUNK*D_INNER
    int d = (int)(gidx & (D_INNER - 1));
    int c = (int)((gidx >> 11) & (NCHUNK - 1));
    int b = (int)(gidx >> (11 + LOG2_NCHUNK));
    float4 al = *(const float4*)&A_log[d * D_STATE + 4 * j];
    float a0 = -__expf(al.x), a1 = -__expf(al.y), a2 = -__expf(al.z), a3 = -__expf(al.w);
    float h0 = 0.f, h1 = 0.f, h2 = 0.f, h3 = 0.f, cum = 0.f;
    long tok0 = (long)b * SEQLEN + c * CHUNK;
    const ushort* dp = deltab + tok0 * D_INNER + d;
    const ushort* xp = xbb + tok0 * D_INNER + d;
    const float* Bp = xpj + tok0 * XPJ_N + DT_RANK + 4 * j;
    for (int t = 0; t < CHUNK; ++t) {
        float dl = bf2f(*dp);
        float x  = bf2f(*xp);
        float4 Bv = *(const float4*)Bp;
        dp += D_INNER; xp += D_INNER; Bp += XPJ_N;
        cum += dl;
        float ux = dl * x;
        h0 = __expf(dl * a0) * h0 + ux * Bv.x;
        h1 = __expf(dl * a1) * h1 + ux * Bv.y;
        h2 = __expf(dl * a2) * h2 + ux * Bv.z;
        h3 = __expf(dl * a3) * h3 + ux * Bv.w;
    }
    long o = gidx * D_STATE + 4 * j;
    *(float4*)&Pout[o] = (float4){__expf(a0 * cum), __expf(a1 * cum), __expf(a2 * cum), __expf(a3 * cum)};
    *(float4*)&Hout[o] = (float4){h0, h1, h2, h3};
}

__global__ __launch_bounds__(256) void scan_chunkscan_kernel(const float* __restrict__ P,
                                                             const float* __restrict__ H,
                                                             float* __restrict__ hinit)
{
    long i = (long)blockIdx.x * 256 + threadIdx.x;  // over BATCH*D_INNER*D_STATE
    int n = (int)(i & (D_STATE - 1));
    int d = (int)((i >> 4) & (D_INNER - 1));
    int b = (int)(i >> 15);
    float h = 0.f;
    for (int c = 0; c < NCHUNK; ++c) {
        long o = ((((long)b * NCHUNK + c) * D_INNER + d) * D_STATE) + n;
        hinit[o] = h;
        h = P[o] * h + H[o];
    }
}

__global__ __launch_bounds__(256) void scan_final_kernel(const ushort* __restrict__ deltab,
                                                         const ushort* __restrict__ xbb,
                                                         const float* __restrict__ xpj,
                                                         const ushort* __restrict__ xzb,
                                                         const float* __restrict__ A_log,
                                                         const float* __restrict__ Dp,
                                                         const float* __restrict__ hinit,
                                                         ushort* __restrict__ yb)
{
    int tid = threadIdx.x;
    int j = tid & 3, grp = tid >> 2;
    long gidx = (long)blockIdx.x * 64 + grp;
    int d = (int)(gidx & (D_INNER - 1));
    int c = (int)((gidx >> 11) & (NCHUNK - 1));
    int b = (int)(gidx >> (11 + LOG2_NCHUNK));
    float4 al = *(const float4*)&A_log[d * D_STATE + 4 * j];
    float a0 = -__expf(al.x), a1 = -__expf(al.y), a2 = -__expf(al.z), a3 = -__expf(al.w);
    float dpar = Dp[d];
    float4 hv = *(const float4*)&hinit[gidx * D_STATE + 4 * j];
    float h0 = hv.x, h1 = hv.y, h2 = hv.z, h3 = hv.w;
    long tok0 = (long)b * SEQLEN + c * CHUNK;
    const ushort* dp = deltab + tok0 * D_INNER + d;
    const ushort* xp = xbb + tok0 * D_INNER + d;
    const float* Bp = xpj + tok0 * XPJ_N + DT_RANK + 4 * j;
    const float* Cp = Bp + D_STATE;
    const ushort* zp = xzb + tok0 * NPROJ + D_INNER + d;
    ushort* yp = yb + tok0 * D_INNER + d;
    for (int t = 0; t < CHUNK; ++t) {
        float dl = bf2f(*dp);
        float x  = bf2f(*xp);
        float4 Bv = *(const float4*)Bp;
        float4 Cv = *(const float4*)Cp;
        dp += D_INNER; xp += D_INNER; Bp += XPJ_N; Cp += XPJ_N;
        float ux = dl * x;
        h0 = __expf(dl * a0) * h0 + ux * Bv.x;
        h1 = __expf(dl * a1) * h1 + ux * Bv.y;
        h2 = __expf(dl * a2) * h2 + ux * Bv.z;
        h3 = __expf(dl * a3) * h3 + ux * Bv.w;
        float p = h0 * Cv.x + h1 * Cv.y + h2 * Cv.z + h3 * Cv.w;
        p += __shfl_xor(p, 1);
        p += __shfl_xor(p, 2);
        if (j == 0) {
            float z = bf2f(*zp);
            float y = p + x * dpar;
            *yp = f2bf_bits(y * (z * sigmoidf_(z)));
        }
        zp += NPROJ; yp += D_INNER;
    }
}

extern "C" void kernel_launch(void* const* d_in, const int* in_sizes, int n_in,
                              void* d_out, int out_size, void* d_ws, size_t ws_size,
                              hipStream_t stream) {
    const float* x         = (const float*)d_in[0];
    const float* ln_gamma  = (const float*)d_in[1];
    const float* ln_beta   = (const float*)d_in[2];
    const float* in_proj_w = (const float*)d_in[3];
    const float* conv_w    = (const float*)d_in[4];
    const float* conv_b    = (const float*)d_in[5];
    const float* x_proj_w  = (const float*)d_in[6];
    const float* dt_proj_w = (const float*)d_in[7];
    const float* dt_proj_b = (const float*)d_in[8];
    const float* A_log     = (const float*)d_in[9];
    const float* D_param   = (const float*)d_in[10];
    const float* out_proj_w= (const float*)d_in[11];
    float* out = (float*)d_out;

    float* ws = (float*)d_ws;
    // Arena slots (floats), same 23.4M-float footprint as before:
    float* h     = ws;                               // 2,097,152
    float* xz    = h     + (long)NTOK * D_MODEL;     // 8,388,608
    float* xb    = xz    + (long)NTOK * NPROJ;       // 4,194,304
    float* xpj   = xb    + (long)NTOK * D_INNER;     //   327,680
    float* delta = xpj   + (long)NTOK * XPJ_N;       // 4,194,304
    float* yfin  = delta + (long)NTOK * D_INNER;     // 4,194,304

    const long PH = (long)BATCH * NCHUNK * D_INNER * D_STATE;   // 2,097,152 floats
    // Aliased scratch, lifetimes stream-ordered:
    ushort* h_bf16   = (ushort*)h;             // ln → gemm2
    ushort* DTT      = (ushort*)(h + 1048576); // dt_proj_w^T bf16 (131k f); 3b → gemm5
    float*  hinit    = h;                      // chunkscan → scan_final (fills h slot; DTT dead)
    ushort* xz_bf16  = (ushort*)xz;            // gemm2 out (4.19M f used of 8.39M)
    ushort* W7T      = (ushort*)(xz + 4194304);// out_proj_w^T bf16 (1.05M f); second half of xz slot
    ushort* W2T      = (ushort*)xb;            // in_proj_w^T bf16 (2.1M f); dead after gemm2
    ushort* xb_bf16  = (ushort*)xb;            // conv out (2.1M f); overwrites W2T ✓
    ushort* XPT      = (ushort*)xpj;           // x_proj_w^T bf16 (164k f); dead after gemm4
    ushort* delta_bf16 = (ushort*)delta;       // gemm5 out (2.1M f of 4.19M slot)
    float*  Ppart    = yfin;                   // gemm4 partials (2.62M f); dead after reduce_xpj
    ushort* dtr      = (ushort*)(yfin + (long)SPLITK * NTOK * XPJ_N); // reduce → gemm5
    float*  Pbuf     = yfin;                   // scan P [PH]
    float*  Hbuf     = yfin + PH;              // scan H [PH] (fills yfin slot)
    ushort* y_bf16   = (ushort*)yfin;          // scan_final out (P/H dead after chunkscan)
    float*  PpartO   = xb;                     // out_proj partials [4][2048][1024] = 8.39M f
                                               // in xb+xpj+delta span (8.72M f), all dead ✓

    // 0a. weight transposes (W2T, W7T; W7T region never otherwise used)
    transpose_bf16_kernel<<<dim3(NPROJ / 64, D_MODEL / 64), 256, 0, stream>>>(
        in_proj_w, W2T, D_MODEL, NPROJ);
    transpose_bf16_kernel<<<dim3(D_MODEL / 64, D_INNER / 64), 256, 0, stream>>>(
        out_proj_w, W7T, D_INNER, D_MODEL);

    // 1. LayerNorm → bf16
    ln_kernel<<<NTOK, 256, 0, stream>>>(x, ln_gamma, ln_beta, h_bf16);

    // 2. xz = h @ in_proj_w (MFMA, bf16 out) [2048,1024]x[1024,4096]
    gemm_mfma_kernel<0, 1><<<dim3(NPROJ / 128, NTOK / 128), 256, 0, stream>>>(
        h_bf16, W2T, nullptr, nullptr, nullptr, xz_bf16,
        NTOK, NPROJ, D_MODEL, D_MODEL, D_MODEL);

    // 3. conv4 + bias + SiLU (bf16 in/out)
    conv_silu_kernel<<<(NTOK * D_INNER) / 256, 256, 0, stream>>>(
        xz_bf16, conv_w, conv_b, xb_bf16);

    // 3b. XPT = x_proj_w^T ; DTT = dt_proj_w^T
    transpose_bf16_kernel<<<dim3((XPJ_N + 63) / 64, D_INNER / 64), 256, 0, stream>>>(
        x_proj_w, XPT, D_INNER, XPJ_N);
    transpose_bf16_kernel<<<dim3(D_INNER / 64, DT_RANK / 64), 256, 0, stream>>>(
        dt_proj_w, DTT, DT_RANK, D_INNER);

    // 4. xpj partials (split-K MFMA) then reduce → xpj f32 + dtr bf16
    gemm4_mfma_kernel<<<dim3(SPLITK, NTOK / 64), 256, 0, stream>>>(
        xb_bf16, XPT, Ppart, NTOK, D_INNER);
    reduce_xpj_kernel<<<(NTOK * XPJ_N) / 256, 256, 0, stream>>>(Ppart, xpj, dtr);

    // 5. delta = softplus(dt_r @ dt_proj_w + b) (MFMA 128x64, bf16 out)
    gemm_mfma64_kernel<1, 1><<<dim3(D_INNER / 64, NTOK / 128), 256, 0, stream>>>(
        dtr, DTT, dt_proj_b, nullptr, nullptr, delta_bf16, NTOK, D_INNER, DT_RANK);

    // 6. chunked selective scan (4 lanes/channel, CHUNK=32, bf16 activations)
    scan_partial_kernel<<<(BATCH * NCHUNK * D_INNER) / 64, 256, 0, stream>>>(
        delta_bf16, xb_bf16, xpj, A_log, Pbuf, Hbuf);
    scan_chunkscan_kernel<<<(BATCH * D_INNER * D_STATE) / 256, 256, 0, stream>>>(
        Pbuf, Hbuf, hinit);
    scan_final_kernel<<<(BATCH * NCHUNK * D_INNER) / 64, 256, 0, stream>>>(
        delta_bf16, xb_bf16, xpj, xz_bf16, A_log, D_param, hinit, y_bf16);

    // 7. out_proj split-K=4: partials then fused reduce+residual
    gemm_mfma_kernel<0, 0><<<dim3(D_MODEL / 128, NTOK / 128, OP_SPLITK), 256, 0, stream>>>(
        y_bf16, W7T, nullptr, nullptr, PpartO, nullptr, NTOK, D_MODEL, D_INNER / OP_SPLITK,
        D_INNER, D_INNER);
    reduce_out_kernel<<<(NTOK * D_MODEL / 4) / 256, 256, 0, stream>>>(PpartO, x, out);
}